// Round 1
// baseline (3868.588 us; speedup 1.0000x reference)
//
#include <hip/hip_runtime.h>
#include <cstdint>
#include <cmath>

// ---------------- constants ----------------
namespace {
constexpr int BATCH = 4;
constexpr int CIN   = 512;
constexpr int CMID  = 512;
constexpr int HSZ   = 64, WSZ = 64, HWP = 4096;
constexpr int NA    = 36864;          // HW * 9 anchors
constexpr int NIN_  = 6000;
constexpr int NOUT2 = 300;

// d_out layout (float offsets)
constexpr size_t O_SC  = 0;           // rpn_scores (4,36864,2)
constexpr size_t O_LC  = 294912;      // rpn_locs   (4,36864,4)
constexpr size_t O_ROI = 884736;      // rois       (1200,4)
constexpr size_t O_IDX = 889536;      // roi_indices(1200)
constexpr size_t O_ANC = 890736;      // anchors    (36864,4)

// d_ws layout (float offsets). Phase A: h + wT. Phase B (post-K2) aliases h.
constexpr size_t W_H    = 0;          // 8388608 floats (conv hidden, NCHW)
constexpr size_t W_WT   = 8388608;    // 2359296 floats (transposed conv_w)
constexpr size_t W_R4   = 0;          // 589824  rois per anchor (aliases h: used after K2 only)
constexpr size_t W_SK   = 589824;     // 147456  score keys (fg or -inf)
constexpr size_t W_HIST = 737280;     // 16384 ints (4 x 4096 bins)
constexpr size_t W_CNT  = 753664;     // 4 ints
constexpr size_t W_CUT  = 753668;     // 4 ints (pad to 753728)
constexpr size_t W_CIDX = 753728;     // 147456 ints  candidate anchor idx
constexpr size_t W_CKEY = 901184;     // 294912 floats = 147456 u64 keys (8B aligned)
constexpr size_t W_RS   = 1196096;    // 96000  sorted rois (4,6000,4)
constexpr size_t W_VS   = 1292096;    // 24000 ints sorted validity
} // namespace

// ---------------- K0: transpose conv_w (co,ci,ky,kx) -> (ci*9+kk, co) ----------------
__global__ __launch_bounds__(256) void k0_transpose(const float* __restrict__ w,
                                                    float* __restrict__ wT) {
    int o = blockIdx.x * 256 + threadIdx.x;     // 2359296 total
    int co = o & 511;
    int r  = o >> 9;                            // ci*9 + kk
    int ci = r / 9;
    int kk = r - ci * 9;
    wT[o] = w[(co * CIN + ci) * 9 + kk];
}

// ---------------- K1: 3x3 conv + bias + ReLU (fp32) ----------------
// grid (32 px-tiles of 2 rows, 4 co-groups of 128, 4 batch); block 256
// thread computes 8 co x 8 px (one image row segment)
__global__ __launch_bounds__(256, 2) void k1_conv3(const float* __restrict__ x,
                                                   const float* __restrict__ wT,
                                                   const float* __restrict__ bias,
                                                   float* __restrict__ h) {
    const int pt  = blockIdx.x;
    const int cg  = blockIdx.y;
    const int b   = blockIdx.z;
    const int y0  = pt * 2;
    const int co0 = cg * 128;
    const int t   = threadIdx.x;
    const int tx  = t & 15, ty = t >> 4;
    const int rowl = tx >> 3;            // which of the 2 output rows
    const int x0   = (tx & 7) * 8;       // 8 consecutive x

    __shared__ __align__(16) float xs[1152];   // [ci(4)][row(4)][72] ; col c -> x = c-1
    __shared__ __align__(16) float wsm[4608];  // [ci(4)*9+kk][128]

    // precompute x-staging slots (5 strided slots of 256)
    int xaddr[5], xoff[5];
#pragma unroll
    for (int s = 0; s < 5; ++s) {
        int idx = t + s * 256;
        int addr = -1, off = -1;
        if (idx < 1152) {
            addr = idx;
            int cir = idx / 288;
            int rem = idx - cir * 288;
            int row = rem / 72;
            int cc  = rem - row * 72;
            int xg = cc - 1;
            int yg = y0 - 1 + row;
            if (cc >= 1 && cc <= 64 && yg >= 0 && yg < HSZ)
                off = (b * CIN + cir) * HWP + yg * WSZ + xg;
        }
        xaddr[s] = addr; xoff[s] = off;
    }
    // precompute w-staging slots (float4 each; 1152 float4 total)
    int waddr[5], woff[5];
#pragma unroll
    for (int s = 0; s < 5; ++s) {
        int idx = t + s * 256;
        if (idx < 1152) {
            int co4 = (idx & 31) * 4;
            int rk  = idx >> 5;              // 0..35
            waddr[s] = rk * 128 + co4;
            woff[s]  = rk * 512 + co0 + co4;
        } else { waddr[s] = -1; woff[s] = 0; }
    }

    float acc[8][8];
#pragma unroll
    for (int c = 0; c < 8; ++c)
#pragma unroll
        for (int p = 0; p < 8; ++p) acc[c][p] = 0.f;

    for (int ci0 = 0; ci0 < CIN; ci0 += 4) {
#pragma unroll
        for (int s = 0; s < 5; ++s) {
            if (xaddr[s] >= 0) {
                float v = 0.f;
                if (xoff[s] >= 0) v = x[xoff[s] + ci0 * HWP];
                xs[xaddr[s]] = v;
            }
        }
#pragma unroll
        for (int s = 0; s < 5; ++s) {
            if (waddr[s] >= 0)
                *(float4*)&wsm[waddr[s]] =
                    *(const float4*)&wT[(size_t)ci0 * 4608 + woff[s]];
        }
        __syncthreads();
#pragma unroll 1
        for (int ci = 0; ci < 4; ++ci) {
#pragma unroll
            for (int ky = 0; ky < 3; ++ky) {
                const float* xr = &xs[ci * 288 + (rowl + ky) * 72 + x0];
                float4 xa = *(const float4*)(xr);
                float4 xb = *(const float4*)(xr + 4);
                float2 xc = *(const float2*)(xr + 8);
                float xv[10] = {xa.x, xa.y, xa.z, xa.w, xb.x, xb.y, xb.z, xb.w, xc.x, xc.y};
#pragma unroll
                for (int kx = 0; kx < 3; ++kx) {
                    const float* wr = &wsm[(ci * 9 + ky * 3 + kx) * 128 + ty * 8];
                    float4 wa = *(const float4*)(wr);
                    float4 wb = *(const float4*)(wr + 4);
                    float wv[8] = {wa.x, wa.y, wa.z, wa.w, wb.x, wb.y, wb.z, wb.w};
#pragma unroll
                    for (int c = 0; c < 8; ++c)
#pragma unroll
                        for (int p = 0; p < 8; ++p)
                            acc[c][p] = fmaf(wv[c], xv[p + kx], acc[c][p]);
                }
            }
        }
        __syncthreads();
    }

    const int yrow = y0 + rowl;
#pragma unroll
    for (int c = 0; c < 8; ++c) {
        int co = co0 + ty * 8 + c;
        float bv = bias[co];
        float4 o0, o1;
        o0.x = fmaxf(acc[c][0] + bv, 0.f);
        o0.y = fmaxf(acc[c][1] + bv, 0.f);
        o0.z = fmaxf(acc[c][2] + bv, 0.f);
        o0.w = fmaxf(acc[c][3] + bv, 0.f);
        o1.x = fmaxf(acc[c][4] + bv, 0.f);
        o1.y = fmaxf(acc[c][5] + bv, 0.f);
        o1.z = fmaxf(acc[c][6] + bv, 0.f);
        o1.w = fmaxf(acc[c][7] + bv, 0.f);
        size_t base = ((size_t)(b * CMID + co)) * HWP + yrow * WSZ + x0;
        *(float4*)&h[base]     = o0;
        *(float4*)&h[base + 4] = o1;
    }
}

// ---------------- K2: 1x1 convs (score 18 + loc 36) -> d_out in NHWC-anchor layout ----------
// grid (64 rows, 4 batch); block 256; thread = 4 channels x 4 px
__global__ __launch_bounds__(256) void k2_conv1(const float* __restrict__ h,
                                                const float* __restrict__ sw,
                                                const float* __restrict__ sb,
                                                const float* __restrict__ lw,
                                                const float* __restrict__ lb,
                                                float* __restrict__ out) {
    const int y = blockIdx.x;
    const int b = blockIdx.y;
    const int t = threadIdx.x;
    const int c4  = (t & 15) * 4;
    const int px4 = (t >> 4) * 4;
    __shared__ __align__(16) float hs[1024];        // [ci(16)][px(64)]
    __shared__ __align__(16) float wsm[16 * 68];    // [ci][c] padded

    float acc[4][4];
#pragma unroll
    for (int i = 0; i < 4; ++i)
#pragma unroll
        for (int j = 0; j < 4; ++j) acc[i][j] = 0.f;

    const int s_px = (t & 15) * 4;
    const int s_ci = t >> 4;
    for (int ci0 = 0; ci0 < CMID; ci0 += 16) {
        *(float4*)&hs[s_ci * 64 + s_px] =
            *(const float4*)&h[((size_t)(b * CMID + ci0 + s_ci)) * HWP + y * 64 + s_px];
#pragma unroll
        for (int k = 0; k < 4; ++k) {
            int idx = k * 256 + t;
            int ci = idx & 15, c = idx >> 4;
            float v = 0.f;
            if (c < 18) v = sw[c * 512 + ci0 + ci];
            else if (c < 54) v = lw[(c - 18) * 512 + ci0 + ci];
            wsm[ci * 68 + c] = v;
        }
        __syncthreads();
#pragma unroll
        for (int ci = 0; ci < 16; ++ci) {
            float4 hv = *(const float4*)&hs[ci * 64 + px4];
            float4 wv = *(const float4*)&wsm[ci * 68 + c4];
            acc[0][0] = fmaf(wv.x, hv.x, acc[0][0]);
            acc[0][1] = fmaf(wv.x, hv.y, acc[0][1]);
            acc[0][2] = fmaf(wv.x, hv.z, acc[0][2]);
            acc[0][3] = fmaf(wv.x, hv.w, acc[0][3]);
            acc[1][0] = fmaf(wv.y, hv.x, acc[1][0]);
            acc[1][1] = fmaf(wv.y, hv.y, acc[1][1]);
            acc[1][2] = fmaf(wv.y, hv.z, acc[1][2]);
            acc[1][3] = fmaf(wv.y, hv.w, acc[1][3]);
            acc[2][0] = fmaf(wv.z, hv.x, acc[2][0]);
            acc[2][1] = fmaf(wv.z, hv.y, acc[2][1]);
            acc[2][2] = fmaf(wv.z, hv.z, acc[2][2]);
            acc[2][3] = fmaf(wv.z, hv.w, acc[2][3]);
            acc[3][0] = fmaf(wv.w, hv.x, acc[3][0]);
            acc[3][1] = fmaf(wv.w, hv.y, acc[3][1]);
            acc[3][2] = fmaf(wv.w, hv.z, acc[3][2]);
            acc[3][3] = fmaf(wv.w, hv.w, acc[3][3]);
        }
        __syncthreads();
    }

#pragma unroll
    for (int cc = 0; cc < 4; ++cc) {
        int c = c4 + cc;
        if (c >= 54) break;
        float bv = (c < 18) ? sb[c] : lb[c - 18];
#pragma unroll
        for (int pp = 0; pp < 4; ++pp) {
            int px = y * 64 + px4 + pp;
            float v = acc[cc][pp] + bv;
            if (c < 18)
                out[O_SC + (size_t)b * 73728 + (size_t)px * 18 + c] = v;
            else
                out[O_LC + (size_t)b * 147456 + (size_t)px * 36 + (c - 18)] = v;
        }
    }
}

// ---------------- K3: anchors + softmax-fg + loc2bbox + clip + histogram ----------------
// grid (144, 4); block 256 -> one thread per anchor
__global__ __launch_bounds__(256) void k3_prop(float* __restrict__ out,
                                               float* __restrict__ rois4,
                                               float* __restrict__ skey,
                                               int* __restrict__ hist) {
    __shared__ int lh[4096];
    const int t = threadIdx.x;
    for (int k = t; k < 4096; k += 256) lh[k] = 0;
    __syncthreads();

    const int p = blockIdx.x * 256 + t;
    const int b = blockIdx.y;
    const int px = p / 9;
    const int a  = p - px * 9;
    const int yy = px >> 6, xx = px & 63;
    const int ri = a / 3, si = a - ri * 3;
    const double rat[3] = {0.5, 1.0, 2.0};
    const double scl[3] = {8.0, 16.0, 32.0};
    double hhd = 16.0 * scl[si] * sqrt(rat[ri]);
    double wwd = 16.0 * scl[si] * sqrt(1.0 / rat[ri]);
    float a0 = (float)(8.0 - hhd / 2.0), a1 = (float)(8.0 - wwd / 2.0);
    float a2 = (float)(8.0 + hhd / 2.0), a3 = (float)(8.0 + wwd / 2.0);
    float sy = (float)(yy * 16), sx = (float)(xx * 16);
    float A0 = sy + a0, A1 = sx + a1, A2 = sy + a2, A3 = sx + a3;
    if (b == 0) {
        float4 av; av.x = A0; av.y = A1; av.z = A2; av.w = A3;
        *(float4*)&out[O_ANC + (size_t)p * 4] = av;
    }
    const float* sc = out + O_SC + (size_t)b * 73728 + (size_t)px * 18 + a * 2;
    float s0 = sc[0], s1 = sc[1];
    float m = fmaxf(s0, s1);
    float e0 = expf(s0 - m), e1 = expf(s1 - m);
    float fg = e1 / (e0 + e1);
    const float* lc = out + O_LC + (size_t)b * 147456 + (size_t)px * 36 + a * 4;
    float dy = lc[0], dxv = lc[1], dh = lc[2], dwv = lc[3];
    float ah = A2 - A0, aw = A3 - A1;
    float cy = A0 + 0.5f * ah, cx = A1 + 0.5f * aw;
    float cty = dy * ah + cy, ctx = dxv * aw + cx;
    float th = expf(dh) * ah, tw = expf(dwv) * aw;
    float ry1 = cty - 0.5f * th, rx1 = ctx - 0.5f * tw;
    float ry2 = cty + 0.5f * th, rx2 = ctx + 0.5f * tw;
    float y1 = fminf(fmaxf(ry1, 0.f), 1024.f);
    float y2 = fminf(fmaxf(ry2, 0.f), 1024.f);
    float x1 = fminf(fmaxf(rx1, 0.f), 1024.f);
    float x2 = fminf(fmaxf(rx2, 0.f), 1024.f);
    bool valid = ((y2 - y1) >= 16.f) && ((x2 - x1) >= 16.f);
    float sk = valid ? fg : -__builtin_inff();
    float4 rv; rv.x = y1; rv.y = x1; rv.z = y2; rv.w = x2;
    *(float4*)&rois4[((size_t)b * NA + p) * 4] = rv;
    skey[(size_t)b * NA + p] = sk;
    unsigned u = __float_as_uint(sk);
    u = (u & 0x80000000u) ? ~u : (u | 0x80000000u);
    atomicAdd(&lh[u >> 20], 1);
    __syncthreads();
    for (int k = t; k < 4096; k += 256) {
        int v = lh[k];
        if (v) atomicAdd(&hist[b * 4096 + k], v);
    }
}

// ---------------- K4b: find cutoff bin (suffix count >= 6000) ----------------
__global__ __launch_bounds__(256) void k4b_scan(const int* __restrict__ hist,
                                                int* __restrict__ cut) {
    __shared__ int hl[4096];
    __shared__ int tsum[256];
    const int t = threadIdx.x;
    for (int b = 0; b < BATCH; ++b) {
        for (int k = t; k < 4096; k += 256) hl[k] = hist[b * 4096 + k];
        __syncthreads();
        int s = 0;
#pragma unroll
        for (int j = 0; j < 16; ++j) s += hl[t * 16 + j];
        tsum[t] = s;
        __syncthreads();
        if (t == 0) {
            int run = 0;
            for (int tt = 255; tt >= 0; --tt) { int tmp = tsum[tt]; tsum[tt] = run; run += tmp; }
        }
        __syncthreads();
        int run = tsum[t];
        for (int v = t * 16 + 15; v >= t * 16; --v) {
            int prev = run;
            run += hl[v];
            if (run >= NIN_ && prev < NIN_) cut[b] = v;
        }
        __syncthreads();
    }
}

// ---------------- K4c: compact candidates (bin >= cut) ----------------
__global__ __launch_bounds__(256) void k4c_compact(const float* __restrict__ skey,
                                                   const int* __restrict__ cut,
                                                   int* __restrict__ cnt,
                                                   int* __restrict__ cidx,
                                                   unsigned long long* __restrict__ ckey) {
    const int p = blockIdx.x * 256 + threadIdx.x;
    const int b = blockIdx.y;
    float sk = skey[(size_t)b * NA + p];
    unsigned u = __float_as_uint(sk);
    u = (u & 0x80000000u) ? ~u : (u | 0x80000000u);
    if ((int)(u >> 20) >= cut[b]) {
        int pos = atomicAdd(&cnt[b], 1);
        cidx[(size_t)b * NA + pos] = p;
        // 48-bit key: score bits (monotone) then inverted index -> unique, matches
        // stable argsort(-s) tie-breaking (lower index wins on equal score)
        ckey[(size_t)b * NA + pos] =
            ((unsigned long long)u << 16) | (unsigned long long)(36863 - p);
    }
}

// ---------------- K4d: exact rank among candidates + scatter sorted top-6000 ----------------
__global__ __launch_bounds__(256) void k4d_rank(const int* __restrict__ cnt,
                                                const int* __restrict__ cidx,
                                                const unsigned long long* __restrict__ ckey,
                                                const float* __restrict__ rois4,
                                                float* __restrict__ rois_s,
                                                int* __restrict__ valid_s) {
    const int b = blockIdx.y;
    const int C = cnt[b];
    const int gi = blockIdx.x * 256 + threadIdx.x;
    const bool act = gi < C;
    const unsigned long long mk = act ? ckey[(size_t)b * NA + gi] : 0ULL;
    __shared__ unsigned long long kl[512];
    int rank = 0;
    for (int c0 = 0; c0 < C; c0 += 512) {
        __syncthreads();
#pragma unroll
        for (int kk = 0; kk < 2; ++kk) {
            int k = threadIdx.x + kk * 256;
            int src = c0 + k;
            kl[k] = (src < C) ? ckey[(size_t)b * NA + src] : 0ULL;
        }
        __syncthreads();
        if (act) {
            int n = min(512, C - c0);
            int j = 0;
            for (; j + 4 <= n; j += 4) {
                rank += (kl[j]     > mk);
                rank += (kl[j + 1] > mk);
                rank += (kl[j + 2] > mk);
                rank += (kl[j + 3] > mk);
            }
            for (; j < n; ++j) rank += (kl[j] > mk);
        }
    }
    if (act && rank < NIN_) {
        int src = cidx[(size_t)b * NA + gi];
        const float4 bx = *(const float4*)&rois4[((size_t)b * NA + src) * 4];
        *(float4*)&rois_s[((size_t)b * NIN_ + rank) * 4] = bx;
        valid_s[(size_t)b * NIN_ + rank] = ((unsigned)(mk >> 16) != 0x007FFFFFu) ? 1 : 0;
    }
}

// ---------------- K6: sequential greedy NMS, early-exit at 300 kept ----------------
// one block per batch; suppression pass fused with next-unsuppressed-min reduction
__global__ __launch_bounds__(256) void k6_nms(const float* __restrict__ rois_s,
                                              const int* __restrict__ valid_s,
                                              float* __restrict__ out) {
    const int b = blockIdx.x, t = threadIdx.x;
    __shared__ unsigned char sup[NIN_];
    __shared__ int wvmin[2][4];
    for (int j = t; j < NIN_; j += 256) sup[j] = valid_s[b * NIN_ + j] ? 0 : 1;
    for (int k = t; k < NOUT2 * 4; k += 256) out[O_ROI + (size_t)b * NOUT2 * 4 + k] = 0.f;
    for (int k = t; k < NOUT2; k += 256) out[O_IDX + (size_t)b * NOUT2 + k] = (float)b;
    __syncthreads();
    const float* bb = rois_s + (size_t)b * NIN_ * 4;
    const int wid = t >> 6, lid = t & 63;
    int i = -1, kept = 0, par = 0;
    while (true) {
        int lmin = 0x7FFFFFFF;
        float b0 = 0, b1 = 0, b2 = 0, b3 = 0, ai = 0;
        if (i >= 0) {
            b0 = bb[i * 4]; b1 = bb[i * 4 + 1]; b2 = bb[i * 4 + 2]; b3 = bb[i * 4 + 3];
            ai = (b2 - b0) * (b3 - b1);
        }
        for (int j = i + 1 + t; j < NIN_; j += 256) {
            if (sup[j]) continue;
            if (i >= 0) {
                const float4 bj = *(const float4*)&bb[(size_t)j * 4];
                float yy1 = fmaxf(b0, bj.x), xx1 = fmaxf(b1, bj.y);
                float yy2 = fminf(b2, bj.z), xx2 = fminf(b3, bj.w);
                float inter = fmaxf(yy2 - yy1, 0.f) * fmaxf(xx2 - xx1, 0.f);
                float aj = (bj.z - bj.x) * (bj.w - bj.y);
                float iou = inter / (ai + aj - inter + 1e-9f);
                if (iou > 0.7f) { sup[j] = 1; continue; }
            }
            lmin = min(lmin, j);
        }
#pragma unroll
        for (int off = 32; off >= 1; off >>= 1) lmin = min(lmin, __shfl_xor(lmin, off, 64));
        if (lid == 0) wvmin[par][wid] = lmin;
        __syncthreads();
        int nxv = min(min(wvmin[par][0], wvmin[par][1]), min(wvmin[par][2], wvmin[par][3]));
        par ^= 1;
        if (nxv == 0x7FFFFFFF) break;
        i = nxv;
        if (t == 0) {
            float4 bx = *(const float4*)&bb[(size_t)i * 4];
            *(float4*)&out[O_ROI + ((size_t)b * NOUT2 + kept) * 4] = bx;
        }
        kept++;
        if (kept >= NOUT2) break;   // ranks >= 300 never reach d_out -> safe early exit
    }
}

// ---------------- launch ----------------
extern "C" void kernel_launch(void* const* d_in, const int* in_sizes, int n_in,
                              void* d_out, int out_size, void* d_ws, size_t ws_size,
                              hipStream_t stream) {
    const float* x       = (const float*)d_in[0];
    const float* conv_w  = (const float*)d_in[1];
    const float* conv_b  = (const float*)d_in[2];
    const float* score_w = (const float*)d_in[3];
    const float* score_b = (const float*)d_in[4];
    const float* loc_w   = (const float*)d_in[5];
    const float* loc_b   = (const float*)d_in[6];
    float* out = (float*)d_out;
    float* ws  = (float*)d_ws;    // needs ~43 MB

    k0_transpose<<<2359296 / 256, 256, 0, stream>>>(conv_w, ws + W_WT);
    k1_conv3<<<dim3(32, 4, 4), 256, 0, stream>>>(x, ws + W_WT, conv_b, ws + W_H);
    k2_conv1<<<dim3(64, 4), 256, 0, stream>>>(ws + W_H, score_w, score_b, loc_w, loc_b, out);
    // zero hist + cnt + cut (region aliases h, so zero AFTER K2 is done with h)
    hipMemsetAsync(ws + W_HIST, 0, (size_t)16448 * 4, stream);
    k3_prop<<<dim3(144, 4), 256, 0, stream>>>(out, ws + W_R4, ws + W_SK, (int*)(ws + W_HIST));
    k4b_scan<<<1, 256, 0, stream>>>((const int*)(ws + W_HIST), (int*)(ws + W_CUT));
    k4c_compact<<<dim3(144, 4), 256, 0, stream>>>(ws + W_SK, (const int*)(ws + W_CUT),
                                                  (int*)(ws + W_CNT), (int*)(ws + W_CIDX),
                                                  (unsigned long long*)(ws + W_CKEY));
    k4d_rank<<<dim3(144, 4), 256, 0, stream>>>((const int*)(ws + W_CNT), (const int*)(ws + W_CIDX),
                                               (const unsigned long long*)(ws + W_CKEY),
                                               ws + W_R4, ws + W_RS, (int*)(ws + W_VS));
    k6_nms<<<BATCH, 256, 0, stream>>>(ws + W_RS, (const int*)(ws + W_VS), out);
}

// Round 2
// 3221.411 us; speedup vs baseline: 1.2009x; 1.2009x over previous
//
#include <hip/hip_runtime.h>
#include <cstdint>
#include <cmath>

// ---------------- constants ----------------
namespace {
constexpr int BATCH = 4;
constexpr int CIN   = 512;
constexpr int CMID  = 512;
constexpr int HSZ   = 64, WSZ = 64, HWP = 4096;
constexpr int NA    = 36864;          // HW * 9 anchors
constexpr int NIN_  = 6000;
constexpr int NOUT2 = 300;

// d_out layout (float offsets)
constexpr size_t O_SC  = 0;           // rpn_scores (4,36864,2)
constexpr size_t O_LC  = 294912;      // rpn_locs   (4,36864,4)
constexpr size_t O_ROI = 884736;      // rois       (1200,4)
constexpr size_t O_IDX = 889536;      // roi_indices(1200)
constexpr size_t O_ANC = 890736;      // anchors    (36864,4)

// d_ws layout (float offsets). Phase A: h + wT. Phase B (post-K2) aliases h.
constexpr size_t W_H    = 0;          // 8388608 floats (conv hidden, NCHW)
constexpr size_t W_WT   = 8388608;    // 2359296 floats (transposed conv_w)
constexpr size_t W_R4   = 0;          // 589824  rois per anchor (aliases h: used after K2 only)
constexpr size_t W_SK   = 589824;     // 147456  score keys (fg or -inf)
constexpr size_t W_HIST = 737280;     // 16384 ints (4 x 4096 bins)
constexpr size_t W_CNT  = 753664;     // 4 ints
constexpr size_t W_CUT  = 753668;     // 4 ints (pad to 753728)
constexpr size_t W_CIDX = 753728;     // 147456 ints  candidate anchor idx
constexpr size_t W_CKEY = 901184;     // 294912 floats = 147456 u64 keys (8B aligned)
constexpr size_t W_RS   = 1196096;    // 96000  sorted rois (4,6000,4)
constexpr size_t W_VS   = 1292096;    // 24000 ints sorted validity
} // namespace

// ---------------- K0: transpose conv_w (co,ci,ky,kx) -> (ci*9+kk, co) ----------------
__global__ __launch_bounds__(256) void k0_transpose(const float* __restrict__ w,
                                                    float* __restrict__ wT) {
    int o = blockIdx.x * 256 + threadIdx.x;     // 2359296 total
    int co = o & 511;
    int r  = o >> 9;                            // ci*9 + kk
    int ci = r / 9;
    int kk = r - ci * 9;
    wT[o] = w[(co * CIN + ci) * 9 + kk];
}

// ---------------- K1: 3x3 conv + bias + ReLU (fp32) ----------------
// grid (32 px-tiles of 2 rows, 4 co-groups of 128, 4 batch); block 256
// thread computes 8 co x 8 px (one image row segment)
__global__ __launch_bounds__(256, 2) void k1_conv3(const float* __restrict__ x,
                                                   const float* __restrict__ wT,
                                                   const float* __restrict__ bias,
                                                   float* __restrict__ h) {
    const int pt  = blockIdx.x;
    const int cg  = blockIdx.y;
    const int b   = blockIdx.z;
    const int y0  = pt * 2;
    const int co0 = cg * 128;
    const int t   = threadIdx.x;
    const int tx  = t & 15, ty = t >> 4;
    const int rowl = tx >> 3;            // which of the 2 output rows
    const int x0   = (tx & 7) * 8;       // 8 consecutive x

    __shared__ __align__(16) float xs[1152];   // [ci(4)][row(4)][72] ; col c -> x = c-1
    __shared__ __align__(16) float wsm[4608];  // [ci(4)*9+kk][128]

    // precompute x-staging slots (5 strided slots of 256)
    int xaddr[5], xoff[5];
#pragma unroll
    for (int s = 0; s < 5; ++s) {
        int idx = t + s * 256;
        int addr = -1, off = -1;
        if (idx < 1152) {
            addr = idx;
            int cir = idx / 288;
            int rem = idx - cir * 288;
            int row = rem / 72;
            int cc  = rem - row * 72;
            int xg = cc - 1;
            int yg = y0 - 1 + row;
            if (cc >= 1 && cc <= 64 && yg >= 0 && yg < HSZ)
                off = (b * CIN + cir) * HWP + yg * WSZ + xg;
        }
        xaddr[s] = addr; xoff[s] = off;
    }
    // precompute w-staging slots (float4 each; 1152 float4 total)
    int waddr[5], woff[5];
#pragma unroll
    for (int s = 0; s < 5; ++s) {
        int idx = t + s * 256;
        if (idx < 1152) {
            int co4 = (idx & 31) * 4;
            int rk  = idx >> 5;              // 0..35
            waddr[s] = rk * 128 + co4;
            woff[s]  = rk * 512 + co0 + co4;
        } else { waddr[s] = -1; woff[s] = 0; }
    }

    float acc[8][8];
#pragma unroll
    for (int c = 0; c < 8; ++c)
#pragma unroll
        for (int p = 0; p < 8; ++p) acc[c][p] = 0.f;

    for (int ci0 = 0; ci0 < CIN; ci0 += 4) {
#pragma unroll
        for (int s = 0; s < 5; ++s) {
            if (xaddr[s] >= 0) {
                float v = 0.f;
                if (xoff[s] >= 0) v = x[xoff[s] + ci0 * HWP];
                xs[xaddr[s]] = v;
            }
        }
#pragma unroll
        for (int s = 0; s < 5; ++s) {
            if (waddr[s] >= 0)
                *(float4*)&wsm[waddr[s]] =
                    *(const float4*)&wT[(size_t)ci0 * 4608 + woff[s]];
        }
        __syncthreads();
#pragma unroll 1
        for (int ci = 0; ci < 4; ++ci) {
#pragma unroll
            for (int ky = 0; ky < 3; ++ky) {
                const float* xr = &xs[ci * 288 + (rowl + ky) * 72 + x0];
                float4 xa = *(const float4*)(xr);
                float4 xb = *(const float4*)(xr + 4);
                float2 xc = *(const float2*)(xr + 8);
                float xv[10] = {xa.x, xa.y, xa.z, xa.w, xb.x, xb.y, xb.z, xb.w, xc.x, xc.y};
#pragma unroll
                for (int kx = 0; kx < 3; ++kx) {
                    const float* wr = &wsm[(ci * 9 + ky * 3 + kx) * 128 + ty * 8];
                    float4 wa = *(const float4*)(wr);
                    float4 wb = *(const float4*)(wr + 4);
                    float wv[8] = {wa.x, wa.y, wa.z, wa.w, wb.x, wb.y, wb.z, wb.w};
#pragma unroll
                    for (int c = 0; c < 8; ++c)
#pragma unroll
                        for (int p = 0; p < 8; ++p)
                            acc[c][p] = fmaf(wv[c], xv[p + kx], acc[c][p]);
                }
            }
        }
        __syncthreads();
    }

    const int yrow = y0 + rowl;
#pragma unroll
    for (int c = 0; c < 8; ++c) {
        int co = co0 + ty * 8 + c;
        float bv = bias[co];
        float4 o0, o1;
        o0.x = fmaxf(acc[c][0] + bv, 0.f);
        o0.y = fmaxf(acc[c][1] + bv, 0.f);
        o0.z = fmaxf(acc[c][2] + bv, 0.f);
        o0.w = fmaxf(acc[c][3] + bv, 0.f);
        o1.x = fmaxf(acc[c][4] + bv, 0.f);
        o1.y = fmaxf(acc[c][5] + bv, 0.f);
        o1.z = fmaxf(acc[c][6] + bv, 0.f);
        o1.w = fmaxf(acc[c][7] + bv, 0.f);
        size_t base = ((size_t)(b * CMID + co)) * HWP + yrow * WSZ + x0;
        *(float4*)&h[base]     = o0;
        *(float4*)&h[base + 4] = o1;
    }
}

// ---------------- K2: 1x1 convs (score 18 + loc 36) -> d_out in NHWC-anchor layout ----------
// grid (64 rows, 4 batch); block 256; thread = 4 channels x 4 px
__global__ __launch_bounds__(256) void k2_conv1(const float* __restrict__ h,
                                                const float* __restrict__ sw,
                                                const float* __restrict__ sb,
                                                const float* __restrict__ lw,
                                                const float* __restrict__ lb,
                                                float* __restrict__ out) {
    const int y = blockIdx.x;
    const int b = blockIdx.y;
    const int t = threadIdx.x;
    const int c4  = (t & 15) * 4;
    const int px4 = (t >> 4) * 4;
    __shared__ __align__(16) float hs[1024];        // [ci(16)][px(64)]
    __shared__ __align__(16) float wsm[16 * 68];    // [ci][c] padded

    float acc[4][4];
#pragma unroll
    for (int i = 0; i < 4; ++i)
#pragma unroll
        for (int j = 0; j < 4; ++j) acc[i][j] = 0.f;

    const int s_px = (t & 15) * 4;
    const int s_ci = t >> 4;
    for (int ci0 = 0; ci0 < CMID; ci0 += 16) {
        *(float4*)&hs[s_ci * 64 + s_px] =
            *(const float4*)&h[((size_t)(b * CMID + ci0 + s_ci)) * HWP + y * 64 + s_px];
#pragma unroll
        for (int k = 0; k < 4; ++k) {
            int idx = k * 256 + t;
            int ci = idx & 15, c = idx >> 4;
            float v = 0.f;
            if (c < 18) v = sw[c * 512 + ci0 + ci];
            else if (c < 54) v = lw[(c - 18) * 512 + ci0 + ci];
            wsm[ci * 68 + c] = v;
        }
        __syncthreads();
#pragma unroll
        for (int ci = 0; ci < 16; ++ci) {
            float4 hv = *(const float4*)&hs[ci * 64 + px4];
            float4 wv = *(const float4*)&wsm[ci * 68 + c4];
            acc[0][0] = fmaf(wv.x, hv.x, acc[0][0]);
            acc[0][1] = fmaf(wv.x, hv.y, acc[0][1]);
            acc[0][2] = fmaf(wv.x, hv.z, acc[0][2]);
            acc[0][3] = fmaf(wv.x, hv.w, acc[0][3]);
            acc[1][0] = fmaf(wv.y, hv.x, acc[1][0]);
            acc[1][1] = fmaf(wv.y, hv.y, acc[1][1]);
            acc[1][2] = fmaf(wv.y, hv.z, acc[1][2]);
            acc[1][3] = fmaf(wv.y, hv.w, acc[1][3]);
            acc[2][0] = fmaf(wv.z, hv.x, acc[2][0]);
            acc[2][1] = fmaf(wv.z, hv.y, acc[2][1]);
            acc[2][2] = fmaf(wv.z, hv.z, acc[2][2]);
            acc[2][3] = fmaf(wv.z, hv.w, acc[2][3]);
            acc[3][0] = fmaf(wv.w, hv.x, acc[3][0]);
            acc[3][1] = fmaf(wv.w, hv.y, acc[3][1]);
            acc[3][2] = fmaf(wv.w, hv.z, acc[3][2]);
            acc[3][3] = fmaf(wv.w, hv.w, acc[3][3]);
        }
        __syncthreads();
    }

#pragma unroll
    for (int cc = 0; cc < 4; ++cc) {
        int c = c4 + cc;
        if (c >= 54) break;
        float bv = (c < 18) ? sb[c] : lb[c - 18];
#pragma unroll
        for (int pp = 0; pp < 4; ++pp) {
            int px = y * 64 + px4 + pp;
            float v = acc[cc][pp] + bv;
            if (c < 18)
                out[O_SC + (size_t)b * 73728 + (size_t)px * 18 + c] = v;
            else
                out[O_LC + (size_t)b * 147456 + (size_t)px * 36 + (c - 18)] = v;
        }
    }
}

// ---------------- K3: anchors + softmax-fg + loc2bbox + clip + histogram ----------------
// grid (144, 4); block 256 -> one thread per anchor
__global__ __launch_bounds__(256) void k3_prop(float* __restrict__ out,
                                               float* __restrict__ rois4,
                                               float* __restrict__ skey,
                                               int* __restrict__ hist) {
    __shared__ int lh[4096];
    const int t = threadIdx.x;
    for (int k = t; k < 4096; k += 256) lh[k] = 0;
    __syncthreads();

    const int p = blockIdx.x * 256 + t;
    const int b = blockIdx.y;
    const int px = p / 9;
    const int a  = p - px * 9;
    const int yy = px >> 6, xx = px & 63;
    const int ri = a / 3, si = a - ri * 3;
    const double rat[3] = {0.5, 1.0, 2.0};
    const double scl[3] = {8.0, 16.0, 32.0};
    double hhd = 16.0 * scl[si] * sqrt(rat[ri]);
    double wwd = 16.0 * scl[si] * sqrt(1.0 / rat[ri]);
    float a0 = (float)(8.0 - hhd / 2.0), a1 = (float)(8.0 - wwd / 2.0);
    float a2 = (float)(8.0 + hhd / 2.0), a3 = (float)(8.0 + wwd / 2.0);
    float sy = (float)(yy * 16), sx = (float)(xx * 16);
    float A0 = sy + a0, A1 = sx + a1, A2 = sy + a2, A3 = sx + a3;
    if (b == 0) {
        float4 av; av.x = A0; av.y = A1; av.z = A2; av.w = A3;
        *(float4*)&out[O_ANC + (size_t)p * 4] = av;
    }
    const float* sc = out + O_SC + (size_t)b * 73728 + (size_t)px * 18 + a * 2;
    float s0 = sc[0], s1 = sc[1];
    float m = fmaxf(s0, s1);
    float e0 = expf(s0 - m), e1 = expf(s1 - m);
    float fg = e1 / (e0 + e1);
    const float* lc = out + O_LC + (size_t)b * 147456 + (size_t)px * 36 + a * 4;
    float dy = lc[0], dxv = lc[1], dh = lc[2], dwv = lc[3];
    float ah = A2 - A0, aw = A3 - A1;
    float cy = A0 + 0.5f * ah, cx = A1 + 0.5f * aw;
    float cty = dy * ah + cy, ctx = dxv * aw + cx;
    float th = expf(dh) * ah, tw = expf(dwv) * aw;
    float ry1 = cty - 0.5f * th, rx1 = ctx - 0.5f * tw;
    float ry2 = cty + 0.5f * th, rx2 = ctx + 0.5f * tw;
    float y1 = fminf(fmaxf(ry1, 0.f), 1024.f);
    float y2 = fminf(fmaxf(ry2, 0.f), 1024.f);
    float x1 = fminf(fmaxf(rx1, 0.f), 1024.f);
    float x2 = fminf(fmaxf(rx2, 0.f), 1024.f);
    bool valid = ((y2 - y1) >= 16.f) && ((x2 - x1) >= 16.f);
    float sk = valid ? fg : -__builtin_inff();
    float4 rv; rv.x = y1; rv.y = x1; rv.z = y2; rv.w = x2;
    *(float4*)&rois4[((size_t)b * NA + p) * 4] = rv;
    skey[(size_t)b * NA + p] = sk;
    unsigned u = __float_as_uint(sk);
    u = (u & 0x80000000u) ? ~u : (u | 0x80000000u);
    atomicAdd(&lh[u >> 20], 1);
    __syncthreads();
    for (int k = t; k < 4096; k += 256) {
        int v = lh[k];
        if (v) atomicAdd(&hist[b * 4096 + k], v);
    }
}

// ---------------- K4b: find cutoff bin (suffix count >= 6000) ----------------
__global__ __launch_bounds__(256) void k4b_scan(const int* __restrict__ hist,
                                                int* __restrict__ cut) {
    __shared__ int hl[4096];
    __shared__ int tsum[256];
    const int t = threadIdx.x;
    for (int b = 0; b < BATCH; ++b) {
        for (int k = t; k < 4096; k += 256) hl[k] = hist[b * 4096 + k];
        __syncthreads();
        int s = 0;
#pragma unroll
        for (int j = 0; j < 16; ++j) s += hl[t * 16 + j];
        tsum[t] = s;
        __syncthreads();
        if (t == 0) {
            int run = 0;
            for (int tt = 255; tt >= 0; --tt) { int tmp = tsum[tt]; tsum[tt] = run; run += tmp; }
        }
        __syncthreads();
        int run = tsum[t];
        for (int v = t * 16 + 15; v >= t * 16; --v) {
            int prev = run;
            run += hl[v];
            if (run >= NIN_ && prev < NIN_) cut[b] = v;
        }
        __syncthreads();
    }
}

// ---------------- K4c: compact candidates (bin >= cut) ----------------
__global__ __launch_bounds__(256) void k4c_compact(const float* __restrict__ skey,
                                                   const int* __restrict__ cut,
                                                   int* __restrict__ cnt,
                                                   int* __restrict__ cidx,
                                                   unsigned long long* __restrict__ ckey) {
    const int p = blockIdx.x * 256 + threadIdx.x;
    const int b = blockIdx.y;
    float sk = skey[(size_t)b * NA + p];
    unsigned u = __float_as_uint(sk);
    u = (u & 0x80000000u) ? ~u : (u | 0x80000000u);
    if ((int)(u >> 20) >= cut[b]) {
        int pos = atomicAdd(&cnt[b], 1);
        cidx[(size_t)b * NA + pos] = p;
        // 48-bit key: score bits (monotone) then inverted index -> unique, matches
        // stable argsort(-s) tie-breaking (lower index wins on equal score)
        ckey[(size_t)b * NA + pos] =
            ((unsigned long long)u << 16) | (unsigned long long)(36863 - p);
    }
}

// ---------------- K4d: exact rank among candidates + scatter sorted top-6000 ----------------
__global__ __launch_bounds__(256) void k4d_rank(const int* __restrict__ cnt,
                                                const int* __restrict__ cidx,
                                                const unsigned long long* __restrict__ ckey,
                                                const float* __restrict__ rois4,
                                                float* __restrict__ rois_s,
                                                int* __restrict__ valid_s) {
    const int b = blockIdx.y;
    const int C = cnt[b];
    const int gi = blockIdx.x * 256 + threadIdx.x;
    const bool act = gi < C;
    const unsigned long long mk = act ? ckey[(size_t)b * NA + gi] : 0ULL;
    __shared__ unsigned long long kl[512];
    int rank = 0;
    for (int c0 = 0; c0 < C; c0 += 512) {
        __syncthreads();
#pragma unroll
        for (int kk = 0; kk < 2; ++kk) {
            int k = threadIdx.x + kk * 256;
            int src = c0 + k;
            kl[k] = (src < C) ? ckey[(size_t)b * NA + src] : 0ULL;
        }
        __syncthreads();
        if (act) {
            int n = min(512, C - c0);
            int j = 0;
            for (; j + 4 <= n; j += 4) {
                rank += (kl[j]     > mk);
                rank += (kl[j + 1] > mk);
                rank += (kl[j + 2] > mk);
                rank += (kl[j + 3] > mk);
            }
            for (; j < n; ++j) rank += (kl[j] > mk);
        }
    }
    if (act && rank < NIN_) {
        int src = cidx[(size_t)b * NA + gi];
        const float4 bx = *(const float4*)&rois4[((size_t)b * NA + src) * 4];
        *(float4*)&rois_s[((size_t)b * NIN_ + rank) * 4] = bx;
        valid_s[(size_t)b * NIN_ + rank] = ((unsigned)(mk >> 16) != 0x007FFFFFu) ? 1 : 0;
    }
}

// ---------------- K6: sequential greedy NMS, all candidates resident in LDS (SoA) -------
// one block per batch; suppression pass fused with next-unsuppressed-min reduction.
// LDS: 5*6000*4 (SoA boxes+area) + 6000 (sup) + 32 = ~126 KB of the 160 KB/CU.
__global__ __launch_bounds__(256) void k6_nms(const float* __restrict__ rois_s,
                                              const int* __restrict__ valid_s,
                                              float* __restrict__ out) {
    const int b = blockIdx.x, t = threadIdx.x;
    __shared__ float y1s[NIN_], x1s[NIN_], y2s[NIN_], x2s[NIN_], ars[NIN_];
    __shared__ unsigned char sup[NIN_];
    __shared__ int wvmin[2][4];
    const float* bb = rois_s + (size_t)b * NIN_ * 4;
    for (int j = t; j < NIN_; j += 256) {
        const float4 v = *(const float4*)&bb[(size_t)j * 4];
        y1s[j] = v.x; x1s[j] = v.y; y2s[j] = v.z; x2s[j] = v.w;
        ars[j] = (v.z - v.x) * (v.w - v.y);
        sup[j] = valid_s[b * NIN_ + j] ? 0 : 1;
    }
    for (int k = t; k < NOUT2 * 4; k += 256) out[O_ROI + (size_t)b * NOUT2 * 4 + k] = 0.f;
    for (int k = t; k < NOUT2; k += 256) out[O_IDX + (size_t)b * NOUT2 + k] = (float)b;
    __syncthreads();
    const int wid = t >> 6, lid = t & 63;
    int i = -1, kept = 0, par = 0;
    while (true) {
        int lmin = 0x7FFFFFFF;
        float b0 = 0, b1 = 0, b2 = 0, b3 = 0, ai = 0;
        if (i >= 0) {
            b0 = y1s[i]; b1 = x1s[i]; b2 = y2s[i]; b3 = x2s[i];
            ai = ars[i];
        }
        for (int j = i + 1 + t; j < NIN_; j += 256) {
            if (sup[j]) continue;
            if (i >= 0) {
                float jy1 = y1s[j], jx1 = x1s[j], jy2 = y2s[j], jx2 = x2s[j];
                float yy1 = fmaxf(b0, jy1), xx1 = fmaxf(b1, jx1);
                float yy2 = fminf(b2, jy2), xx2 = fminf(b3, jx2);
                float inter = fmaxf(yy2 - yy1, 0.f) * fmaxf(xx2 - xx1, 0.f);
                float iou = inter / (ai + ars[j] - inter + 1e-9f);
                if (iou > 0.7f) { sup[j] = 1; continue; }
            }
            lmin = min(lmin, j);
        }
#pragma unroll
        for (int off = 32; off >= 1; off >>= 1) lmin = min(lmin, __shfl_xor(lmin, off, 64));
        if (lid == 0) wvmin[par][wid] = lmin;
        __syncthreads();
        int nxv = min(min(wvmin[par][0], wvmin[par][1]), min(wvmin[par][2], wvmin[par][3]));
        par ^= 1;
        if (nxv == 0x7FFFFFFF) break;
        i = nxv;
        if (t == 0) {
            float4 bx;
            bx.x = y1s[i]; bx.y = x1s[i]; bx.z = y2s[i]; bx.w = x2s[i];
            *(float4*)&out[O_ROI + ((size_t)b * NOUT2 + kept) * 4] = bx;
        }
        kept++;
        if (kept >= NOUT2) break;   // ranks >= 300 never reach d_out -> safe early exit
    }
}

// ---------------- launch ----------------
extern "C" void kernel_launch(void* const* d_in, const int* in_sizes, int n_in,
                              void* d_out, int out_size, void* d_ws, size_t ws_size,
                              hipStream_t stream) {
    const float* x       = (const float*)d_in[0];
    const float* conv_w  = (const float*)d_in[1];
    const float* conv_b  = (const float*)d_in[2];
    const float* score_w = (const float*)d_in[3];
    const float* score_b = (const float*)d_in[4];
    const float* loc_w   = (const float*)d_in[5];
    const float* loc_b   = (const float*)d_in[6];
    float* out = (float*)d_out;
    float* ws  = (float*)d_ws;    // needs ~43 MB

    k0_transpose<<<2359296 / 256, 256, 0, stream>>>(conv_w, ws + W_WT);
    k1_conv3<<<dim3(32, 4, 4), 256, 0, stream>>>(x, ws + W_WT, conv_b, ws + W_H);
    k2_conv1<<<dim3(64, 4), 256, 0, stream>>>(ws + W_H, score_w, score_b, loc_w, loc_b, out);
    // zero hist + cnt + cut (region aliases h, so zero AFTER K2 is done with h)
    hipMemsetAsync(ws + W_HIST, 0, (size_t)16448 * 4, stream);
    k3_prop<<<dim3(144, 4), 256, 0, stream>>>(out, ws + W_R4, ws + W_SK, (int*)(ws + W_HIST));
    k4b_scan<<<1, 256, 0, stream>>>((const int*)(ws + W_HIST), (int*)(ws + W_CUT));
    k4c_compact<<<dim3(144, 4), 256, 0, stream>>>(ws + W_SK, (const int*)(ws + W_CUT),
                                                  (int*)(ws + W_CNT), (int*)(ws + W_CIDX),
                                                  (unsigned long long*)(ws + W_CKEY));
    k4d_rank<<<dim3(144, 4), 256, 0, stream>>>((const int*)(ws + W_CNT), (const int*)(ws + W_CIDX),
                                               (const unsigned long long*)(ws + W_CKEY),
                                               ws + W_R4, ws + W_RS, (int*)(ws + W_VS));
    k6_nms<<<BATCH, 256, 0, stream>>>(ws + W_RS, (const int*)(ws + W_VS), out);
}

// Round 3
// 2483.006 us; speedup vs baseline: 1.5580x; 1.2974x over previous
//
#include <hip/hip_runtime.h>
#include <cstdint>
#include <cmath>

// ---------------- constants ----------------
namespace {
constexpr int BATCH = 4;
constexpr int CIN   = 512;
constexpr int CMID  = 512;
constexpr int HSZ   = 64, WSZ = 64, HWP = 4096;
constexpr int NA    = 36864;          // HW * 9 anchors
constexpr int NIN_  = 6000;
constexpr int NOUT2 = 300;
constexpr int NW    = 94;             // ceil(6000/64) u64 words per bitmask row

// d_out layout (float offsets)
constexpr size_t O_SC  = 0;           // rpn_scores (4,36864,2)
constexpr size_t O_LC  = 294912;      // rpn_locs   (4,36864,4)
constexpr size_t O_ROI = 884736;      // rois       (1200,4)
constexpr size_t O_IDX = 889536;      // roi_indices(1200)
constexpr size_t O_ANC = 890736;      // anchors    (36864,4)

// d_ws layout (float offsets). Phase A: h + wT. Phase B (post-K2) aliases h.
constexpr size_t W_H    = 0;          // 8388608 floats (conv hidden, NCHW)
constexpr size_t W_WT   = 8388608;    // 2359296 floats (transposed conv_w)
constexpr size_t W_R4   = 0;          // 589824  rois per anchor (aliases h: used after K2 only)
constexpr size_t W_SK   = 589824;     // 147456  score keys (fg or -inf)
constexpr size_t W_HIST = 737280;     // 16384 ints (4 x 4096 bins)
constexpr size_t W_CNT  = 753664;     // 4 ints
constexpr size_t W_CUT  = 753668;     // 4 ints (pad to 753728)
constexpr size_t W_CIDX = 753728;     // 147456 ints  candidate anchor idx
constexpr size_t W_CKEY = 901184;     // 294912 floats = 147456 u64 keys (8B aligned)
constexpr size_t W_RS   = 1196096;    // 96000  sorted rois (4,6000,4)
constexpr size_t W_VS   = 1292096;    // 24000 ints sorted validity
constexpr size_t W_MAT  = 1316096;    // 4*6000*94 u64 = 4512000 floats (suppression bits)
} // namespace

// ---------------- K0: transpose conv_w (co,ci,ky,kx) -> (ci*9+kk, co) ----------------
__global__ __launch_bounds__(256) void k0_transpose(const float* __restrict__ w,
                                                    float* __restrict__ wT) {
    int o = blockIdx.x * 256 + threadIdx.x;     // 2359296 total
    int co = o & 511;
    int r  = o >> 9;                            // ci*9 + kk
    int ci = r / 9;
    int kk = r - ci * 9;
    wT[o] = w[(co * CIN + ci) * 9 + kk];
}

// ---------------- K1: 3x3 conv + bias + ReLU (fp32) ----------------
// grid (32 px-tiles of 2 rows, 4 co-groups of 128, 4 batch); block 256
// thread computes 8 co x 8 px (one image row segment)
__global__ __launch_bounds__(256, 2) void k1_conv3(const float* __restrict__ x,
                                                   const float* __restrict__ wT,
                                                   const float* __restrict__ bias,
                                                   float* __restrict__ h) {
    const int pt  = blockIdx.x;
    const int cg  = blockIdx.y;
    const int b   = blockIdx.z;
    const int y0  = pt * 2;
    const int co0 = cg * 128;
    const int t   = threadIdx.x;
    const int tx  = t & 15, ty = t >> 4;
    const int rowl = tx >> 3;            // which of the 2 output rows
    const int x0   = (tx & 7) * 8;       // 8 consecutive x

    __shared__ __align__(16) float xs[1152];   // [ci(4)][row(4)][72] ; col c -> x = c-1
    __shared__ __align__(16) float wsm[4608];  // [ci(4)*9+kk][128]

    // precompute x-staging slots (5 strided slots of 256)
    int xaddr[5], xoff[5];
#pragma unroll
    for (int s = 0; s < 5; ++s) {
        int idx = t + s * 256;
        int addr = -1, off = -1;
        if (idx < 1152) {
            addr = idx;
            int cir = idx / 288;
            int rem = idx - cir * 288;
            int row = rem / 72;
            int cc  = rem - row * 72;
            int xg = cc - 1;
            int yg = y0 - 1 + row;
            if (cc >= 1 && cc <= 64 && yg >= 0 && yg < HSZ)
                off = (b * CIN + cir) * HWP + yg * WSZ + xg;
        }
        xaddr[s] = addr; xoff[s] = off;
    }
    // precompute w-staging slots (float4 each; 1152 float4 total)
    int waddr[5], woff[5];
#pragma unroll
    for (int s = 0; s < 5; ++s) {
        int idx = t + s * 256;
        if (idx < 1152) {
            int co4 = (idx & 31) * 4;
            int rk  = idx >> 5;              // 0..35
            waddr[s] = rk * 128 + co4;
            woff[s]  = rk * 512 + co0 + co4;
        } else { waddr[s] = -1; woff[s] = 0; }
    }

    float acc[8][8];
#pragma unroll
    for (int c = 0; c < 8; ++c)
#pragma unroll
        for (int p = 0; p < 8; ++p) acc[c][p] = 0.f;

    for (int ci0 = 0; ci0 < CIN; ci0 += 4) {
#pragma unroll
        for (int s = 0; s < 5; ++s) {
            if (xaddr[s] >= 0) {
                float v = 0.f;
                if (xoff[s] >= 0) v = x[xoff[s] + ci0 * HWP];
                xs[xaddr[s]] = v;
            }
        }
#pragma unroll
        for (int s = 0; s < 5; ++s) {
            if (waddr[s] >= 0)
                *(float4*)&wsm[waddr[s]] =
                    *(const float4*)&wT[(size_t)ci0 * 4608 + woff[s]];
        }
        __syncthreads();
#pragma unroll 1
        for (int ci = 0; ci < 4; ++ci) {
#pragma unroll
            for (int ky = 0; ky < 3; ++ky) {
                const float* xr = &xs[ci * 288 + (rowl + ky) * 72 + x0];
                float4 xa = *(const float4*)(xr);
                float4 xb = *(const float4*)(xr + 4);
                float2 xc = *(const float2*)(xr + 8);
                float xv[10] = {xa.x, xa.y, xa.z, xa.w, xb.x, xb.y, xb.z, xb.w, xc.x, xc.y};
#pragma unroll
                for (int kx = 0; kx < 3; ++kx) {
                    const float* wr = &wsm[(ci * 9 + ky * 3 + kx) * 128 + ty * 8];
                    float4 wa = *(const float4*)(wr);
                    float4 wb = *(const float4*)(wr + 4);
                    float wv[8] = {wa.x, wa.y, wa.z, wa.w, wb.x, wb.y, wb.z, wb.w};
#pragma unroll
                    for (int c = 0; c < 8; ++c)
#pragma unroll
                        for (int p = 0; p < 8; ++p)
                            acc[c][p] = fmaf(wv[c], xv[p + kx], acc[c][p]);
                }
            }
        }
        __syncthreads();
    }

    const int yrow = y0 + rowl;
#pragma unroll
    for (int c = 0; c < 8; ++c) {
        int co = co0 + ty * 8 + c;
        float bv = bias[co];
        float4 o0, o1;
        o0.x = fmaxf(acc[c][0] + bv, 0.f);
        o0.y = fmaxf(acc[c][1] + bv, 0.f);
        o0.z = fmaxf(acc[c][2] + bv, 0.f);
        o0.w = fmaxf(acc[c][3] + bv, 0.f);
        o1.x = fmaxf(acc[c][4] + bv, 0.f);
        o1.y = fmaxf(acc[c][5] + bv, 0.f);
        o1.z = fmaxf(acc[c][6] + bv, 0.f);
        o1.w = fmaxf(acc[c][7] + bv, 0.f);
        size_t base = ((size_t)(b * CMID + co)) * HWP + yrow * WSZ + x0;
        *(float4*)&h[base]     = o0;
        *(float4*)&h[base + 4] = o1;
    }
}

// ---------------- K2: 1x1 convs (score 18 + loc 36) -> d_out in NHWC-anchor layout ----------
// grid (64 rows, 4 batch); block 256; thread = 4 channels x 4 px
__global__ __launch_bounds__(256) void k2_conv1(const float* __restrict__ h,
                                                const float* __restrict__ sw,
                                                const float* __restrict__ sb,
                                                const float* __restrict__ lw,
                                                const float* __restrict__ lb,
                                                float* __restrict__ out) {
    const int y = blockIdx.x;
    const int b = blockIdx.y;
    const int t = threadIdx.x;
    const int c4  = (t & 15) * 4;
    const int px4 = (t >> 4) * 4;
    __shared__ __align__(16) float hs[1024];        // [ci(16)][px(64)]
    __shared__ __align__(16) float wsm[16 * 68];    // [ci][c] padded

    float acc[4][4];
#pragma unroll
    for (int i = 0; i < 4; ++i)
#pragma unroll
        for (int j = 0; j < 4; ++j) acc[i][j] = 0.f;

    const int s_px = (t & 15) * 4;
    const int s_ci = t >> 4;
    for (int ci0 = 0; ci0 < CMID; ci0 += 16) {
        *(float4*)&hs[s_ci * 64 + s_px] =
            *(const float4*)&h[((size_t)(b * CMID + ci0 + s_ci)) * HWP + y * 64 + s_px];
#pragma unroll
        for (int k = 0; k < 4; ++k) {
            int idx = k * 256 + t;
            int ci = idx & 15, c = idx >> 4;
            float v = 0.f;
            if (c < 18) v = sw[c * 512 + ci0 + ci];
            else if (c < 54) v = lw[(c - 18) * 512 + ci0 + ci];
            wsm[ci * 68 + c] = v;
        }
        __syncthreads();
#pragma unroll
        for (int ci = 0; ci < 16; ++ci) {
            float4 hv = *(const float4*)&hs[ci * 64 + px4];
            float4 wv = *(const float4*)&wsm[ci * 68 + c4];
            acc[0][0] = fmaf(wv.x, hv.x, acc[0][0]);
            acc[0][1] = fmaf(wv.x, hv.y, acc[0][1]);
            acc[0][2] = fmaf(wv.x, hv.z, acc[0][2]);
            acc[0][3] = fmaf(wv.x, hv.w, acc[0][3]);
            acc[1][0] = fmaf(wv.y, hv.x, acc[1][0]);
            acc[1][1] = fmaf(wv.y, hv.y, acc[1][1]);
            acc[1][2] = fmaf(wv.y, hv.z, acc[1][2]);
            acc[1][3] = fmaf(wv.y, hv.w, acc[1][3]);
            acc[2][0] = fmaf(wv.z, hv.x, acc[2][0]);
            acc[2][1] = fmaf(wv.z, hv.y, acc[2][1]);
            acc[2][2] = fmaf(wv.z, hv.z, acc[2][2]);
            acc[2][3] = fmaf(wv.z, hv.w, acc[2][3]);
            acc[3][0] = fmaf(wv.w, hv.x, acc[3][0]);
            acc[3][1] = fmaf(wv.w, hv.y, acc[3][1]);
            acc[3][2] = fmaf(wv.w, hv.z, acc[3][2]);
            acc[3][3] = fmaf(wv.w, hv.w, acc[3][3]);
        }
        __syncthreads();
    }

#pragma unroll
    for (int cc = 0; cc < 4; ++cc) {
        int c = c4 + cc;
        if (c >= 54) break;
        float bv = (c < 18) ? sb[c] : lb[c - 18];
#pragma unroll
        for (int pp = 0; pp < 4; ++pp) {
            int px = y * 64 + px4 + pp;
            float v = acc[cc][pp] + bv;
            if (c < 18)
                out[O_SC + (size_t)b * 73728 + (size_t)px * 18 + c] = v;
            else
                out[O_LC + (size_t)b * 147456 + (size_t)px * 36 + (c - 18)] = v;
        }
    }
}

// ---------------- K3: anchors + softmax-fg + loc2bbox + clip + histogram ----------------
// grid (144, 4); block 256 -> one thread per anchor
__global__ __launch_bounds__(256) void k3_prop(float* __restrict__ out,
                                               float* __restrict__ rois4,
                                               float* __restrict__ skey,
                                               int* __restrict__ hist) {
    __shared__ int lh[4096];
    const int t = threadIdx.x;
    for (int k = t; k < 4096; k += 256) lh[k] = 0;
    __syncthreads();

    const int p = blockIdx.x * 256 + t;
    const int b = blockIdx.y;
    const int px = p / 9;
    const int a  = p - px * 9;
    const int yy = px >> 6, xx = px & 63;
    const int ri = a / 3, si = a - ri * 3;
    const double rat[3] = {0.5, 1.0, 2.0};
    const double scl[3] = {8.0, 16.0, 32.0};
    double hhd = 16.0 * scl[si] * sqrt(rat[ri]);
    double wwd = 16.0 * scl[si] * sqrt(1.0 / rat[ri]);
    float a0 = (float)(8.0 - hhd / 2.0), a1 = (float)(8.0 - wwd / 2.0);
    float a2 = (float)(8.0 + hhd / 2.0), a3 = (float)(8.0 + wwd / 2.0);
    float sy = (float)(yy * 16), sx = (float)(xx * 16);
    float A0 = sy + a0, A1 = sx + a1, A2 = sy + a2, A3 = sx + a3;
    if (b == 0) {
        float4 av; av.x = A0; av.y = A1; av.z = A2; av.w = A3;
        *(float4*)&out[O_ANC + (size_t)p * 4] = av;
    }
    const float* sc = out + O_SC + (size_t)b * 73728 + (size_t)px * 18 + a * 2;
    float s0 = sc[0], s1 = sc[1];
    float m = fmaxf(s0, s1);
    float e0 = expf(s0 - m), e1 = expf(s1 - m);
    float fg = e1 / (e0 + e1);
    const float* lc = out + O_LC + (size_t)b * 147456 + (size_t)px * 36 + a * 4;
    float dy = lc[0], dxv = lc[1], dh = lc[2], dwv = lc[3];
    float ah = A2 - A0, aw = A3 - A1;
    float cy = A0 + 0.5f * ah, cx = A1 + 0.5f * aw;
    float cty = dy * ah + cy, ctx = dxv * aw + cx;
    float th = expf(dh) * ah, tw = expf(dwv) * aw;
    float ry1 = cty - 0.5f * th, rx1 = ctx - 0.5f * tw;
    float ry2 = cty + 0.5f * th, rx2 = ctx + 0.5f * tw;
    float y1 = fminf(fmaxf(ry1, 0.f), 1024.f);
    float y2 = fminf(fmaxf(ry2, 0.f), 1024.f);
    float x1 = fminf(fmaxf(rx1, 0.f), 1024.f);
    float x2 = fminf(fmaxf(rx2, 0.f), 1024.f);
    bool valid = ((y2 - y1) >= 16.f) && ((x2 - x1) >= 16.f);
    float sk = valid ? fg : -__builtin_inff();
    float4 rv; rv.x = y1; rv.y = x1; rv.z = y2; rv.w = x2;
    *(float4*)&rois4[((size_t)b * NA + p) * 4] = rv;
    skey[(size_t)b * NA + p] = sk;
    unsigned u = __float_as_uint(sk);
    u = (u & 0x80000000u) ? ~u : (u | 0x80000000u);
    atomicAdd(&lh[u >> 20], 1);
    __syncthreads();
    for (int k = t; k < 4096; k += 256) {
        int v = lh[k];
        if (v) atomicAdd(&hist[b * 4096 + k], v);
    }
}

// ---------------- K4b: find cutoff bin (suffix count >= 6000) ----------------
__global__ __launch_bounds__(256) void k4b_scan(const int* __restrict__ hist,
                                                int* __restrict__ cut) {
    __shared__ int hl[4096];
    __shared__ int tsum[256];
    const int t = threadIdx.x;
    for (int b = 0; b < BATCH; ++b) {
        for (int k = t; k < 4096; k += 256) hl[k] = hist[b * 4096 + k];
        __syncthreads();
        int s = 0;
#pragma unroll
        for (int j = 0; j < 16; ++j) s += hl[t * 16 + j];
        tsum[t] = s;
        __syncthreads();
        if (t == 0) {
            int run = 0;
            for (int tt = 255; tt >= 0; --tt) { int tmp = tsum[tt]; tsum[tt] = run; run += tmp; }
        }
        __syncthreads();
        int run = tsum[t];
        for (int v = t * 16 + 15; v >= t * 16; --v) {
            int prev = run;
            run += hl[v];
            if (run >= NIN_ && prev < NIN_) cut[b] = v;
        }
        __syncthreads();
    }
}

// ---------------- K4c: compact candidates (bin >= cut) ----------------
__global__ __launch_bounds__(256) void k4c_compact(const float* __restrict__ skey,
                                                   const int* __restrict__ cut,
                                                   int* __restrict__ cnt,
                                                   int* __restrict__ cidx,
                                                   unsigned long long* __restrict__ ckey) {
    const int p = blockIdx.x * 256 + threadIdx.x;
    const int b = blockIdx.y;
    float sk = skey[(size_t)b * NA + p];
    unsigned u = __float_as_uint(sk);
    u = (u & 0x80000000u) ? ~u : (u | 0x80000000u);
    if ((int)(u >> 20) >= cut[b]) {
        int pos = atomicAdd(&cnt[b], 1);
        cidx[(size_t)b * NA + pos] = p;
        // 48-bit key: score bits (monotone) then inverted index -> unique, matches
        // stable argsort(-s) tie-breaking (lower index wins on equal score)
        ckey[(size_t)b * NA + pos] =
            ((unsigned long long)u << 16) | (unsigned long long)(36863 - p);
    }
}

// ---------------- K4d: exact rank among candidates + scatter sorted top-6000 ----------------
__global__ __launch_bounds__(256) void k4d_rank(const int* __restrict__ cnt,
                                                const int* __restrict__ cidx,
                                                const unsigned long long* __restrict__ ckey,
                                                const float* __restrict__ rois4,
                                                float* __restrict__ rois_s,
                                                int* __restrict__ valid_s) {
    const int b = blockIdx.y;
    const int C = cnt[b];
    if (blockIdx.x * 256 >= C) return;   // whole-block early exit (C uniform)
    const int gi = blockIdx.x * 256 + threadIdx.x;
    const bool act = gi < C;
    const unsigned long long mk = act ? ckey[(size_t)b * NA + gi] : 0ULL;
    __shared__ unsigned long long kl[512];
    int rank = 0;
    for (int c0 = 0; c0 < C; c0 += 512) {
        __syncthreads();
#pragma unroll
        for (int kk = 0; kk < 2; ++kk) {
            int k = threadIdx.x + kk * 256;
            int src = c0 + k;
            kl[k] = (src < C) ? ckey[(size_t)b * NA + src] : 0ULL;
        }
        __syncthreads();
        if (act) {
            int n = min(512, C - c0);
            int j = 0;
            for (; j + 4 <= n; j += 4) {
                rank += (kl[j]     > mk);
                rank += (kl[j + 1] > mk);
                rank += (kl[j + 2] > mk);
                rank += (kl[j + 3] > mk);
            }
            for (; j < n; ++j) rank += (kl[j] > mk);
        }
    }
    if (act && rank < NIN_) {
        int src = cidx[(size_t)b * NA + gi];
        const float4 bx = *(const float4*)&rois4[((size_t)b * NA + src) * 4];
        *(float4*)&rois_s[((size_t)b * NIN_ + rank) * 4] = bx;
        valid_s[(size_t)b * NIN_ + rank] = ((unsigned)(mk >> 16) != 0x007FFFFFu) ? 1 : 0;
    }
}

// ---------------- K5a: pairwise suppression bitmask matrix ----------------
// grid (94 rowblocks, 4 batch); block 64 (one wave); thread = row i.
// mat[b][i][w] bit k: IoU(box_i, box_{w*64+k}) > 0.7 AND (w*64+k) > i.
// IoU expression identical (incl. IEEE fp32 div) to the R1/R2 kernel that passed.
__global__ __launch_bounds__(64) void k5_mat(const float* __restrict__ rois_s,
                                             unsigned long long* __restrict__ mat) {
    const int b = blockIdx.y, t = threadIdx.x;
    const int i = blockIdx.x * 64 + t;
    __shared__ float cy1[64], cx1[64], cy2[64], cx2[64], car[64];
    const float* bb = rois_s + (size_t)b * NIN_ * 4;
    const bool rowok = (i < NIN_);
    float r0 = 0, r1 = 0, r2 = 0, r3 = 0, ra = 0;
    if (rowok) {
        float4 v = *(const float4*)&bb[(size_t)i * 4];
        r0 = v.x; r1 = v.y; r2 = v.z; r3 = v.w;
        ra = (v.z - v.x) * (v.w - v.y);
    }
    unsigned long long* mrow = mat + ((size_t)b * NIN_ + (rowok ? i : 0)) * NW;
    for (int cb = 0; cb < NW; ++cb) {
        const int j0 = cb * 64;
        const int j  = j0 + t;
        float4 v;
        if (j < NIN_) v = *(const float4*)&bb[(size_t)j * 4];
        else { v.x = 0; v.y = 0; v.z = 0; v.w = 0; }
        __syncthreads();
        cy1[t] = v.x; cx1[t] = v.y; cy2[t] = v.z; cx2[t] = v.w;
        car[t] = (v.z - v.x) * (v.w - v.y);
        __syncthreads();
        unsigned long long wm = 0;
        if (rowok && (j0 + 63 > i)) {
            const int kbeg = (i + 1 > j0) ? (i + 1 - j0) : 0;
            const int kend = (NIN_ - j0 < 64) ? (NIN_ - j0) : 64;
            for (int k = kbeg; k < kend; ++k) {
                float yy1 = fmaxf(r0, cy1[k]), xx1 = fmaxf(r1, cx1[k]);
                float yy2 = fminf(r2, cy2[k]), xx2 = fminf(r3, cx2[k]);
                float inter = fmaxf(yy2 - yy1, 0.f) * fmaxf(xx2 - xx1, 0.f);
                float iou = inter / (ra + car[k] - inter + 1e-9f);
                if (iou > 0.7f) wm |= (1ull << k);
            }
        }
        if (rowok) mrow[cb] = wm;
    }
}

// ---------------- K5b: serial greedy scan over bitmask ----------------
// grid (4); block 64 (one wave). Suppressed-mask distributed in registers:
// lane l owns words l (A) and 64+l (B, l<30). Kept rows OR their mat row in.
__global__ __launch_bounds__(64) void k5_scan(const unsigned long long* __restrict__ mat,
                                              const float* __restrict__ rois_s,
                                              const int* __restrict__ valid_s,
                                              float* __restrict__ out) {
    const int b = blockIdx.x, t = threadIdx.x;
    for (int k = t; k < NOUT2 * 4; k += 64) out[O_ROI + (size_t)b * NOUT2 * 4 + k] = 0.f;
    for (int k = t; k < NOUT2; k += 64) out[O_IDX + (size_t)b * NOUT2 + k] = (float)b;

    // init suppressed-mask from validity (invalid -> suppressed from the start;
    // it can never be kept and never suppresses -> matches reference semantics)
    unsigned long long A = 0, B = 0;
    for (int w = 0; w < NW; ++w) {
        int i = w * 64 + t;
        int v = (i < NIN_) ? valid_s[b * NIN_ + i] : 0;
        unsigned long long m = __ballot(v == 0);
        if (w < 64) { if (t == w) A = m; }
        else        { if (t == w - 64) B = m; }
    }

    const unsigned long long* mb = mat + (size_t)b * NIN_ * NW;
    const float* bb = rois_s + (size_t)b * NIN_ * 4;
    int kept = 0;
    for (int w = 0; w < NW && kept < NOUT2; ++w) {
        unsigned long long cur = (w < 64) ? __shfl(A, w) : __shfl(B, w - 64);
        unsigned long long avail = ~cur;
        while (avail != 0ull && kept < NOUT2) {
            int bit = __builtin_ctzll(avail);
            int i = w * 64 + bit;
            if (t == 0) {
                float4 bx = *(const float4*)&bb[(size_t)i * 4];
                *(float4*)&out[O_ROI + ((size_t)b * NOUT2 + kept) * 4] = bx;
            }
            kept++;
            if (kept >= NOUT2) break;
            const unsigned long long* row = mb + (size_t)i * NW;
            unsigned long long rA = row[t];
            unsigned long long rB = (t < NW - 64) ? row[64 + t] : 0ull;
            A |= rA; B |= rB;
            unsigned long long rw = (w < 64) ? __shfl(rA, w) : __shfl(rB, w - 64);
            avail &= ~rw;
            avail &= ~(1ull << bit);
        }
    }
}

// ---------------- launch ----------------
extern "C" void kernel_launch(void* const* d_in, const int* in_sizes, int n_in,
                              void* d_out, int out_size, void* d_ws, size_t ws_size,
                              hipStream_t stream) {
    const float* x       = (const float*)d_in[0];
    const float* conv_w  = (const float*)d_in[1];
    const float* conv_b  = (const float*)d_in[2];
    const float* score_w = (const float*)d_in[3];
    const float* score_b = (const float*)d_in[4];
    const float* loc_w   = (const float*)d_in[5];
    const float* loc_b   = (const float*)d_in[6];
    float* out = (float*)d_out;
    float* ws  = (float*)d_ws;    // needs ~43 MB (phase A high-water)

    k0_transpose<<<2359296 / 256, 256, 0, stream>>>(conv_w, ws + W_WT);
    k1_conv3<<<dim3(32, 4, 4), 256, 0, stream>>>(x, ws + W_WT, conv_b, ws + W_H);
    k2_conv1<<<dim3(64, 4), 256, 0, stream>>>(ws + W_H, score_w, score_b, loc_w, loc_b, out);
    // zero hist + cnt + cut (region aliases h, so zero AFTER K2 is done with h)
    hipMemsetAsync(ws + W_HIST, 0, (size_t)16448 * 4, stream);
    k3_prop<<<dim3(144, 4), 256, 0, stream>>>(out, ws + W_R4, ws + W_SK, (int*)(ws + W_HIST));
    k4b_scan<<<1, 256, 0, stream>>>((const int*)(ws + W_HIST), (int*)(ws + W_CUT));
    k4c_compact<<<dim3(144, 4), 256, 0, stream>>>(ws + W_SK, (const int*)(ws + W_CUT),
                                                  (int*)(ws + W_CNT), (int*)(ws + W_CIDX),
                                                  (unsigned long long*)(ws + W_CKEY));
    k4d_rank<<<dim3(144, 4), 256, 0, stream>>>((const int*)(ws + W_CNT), (const int*)(ws + W_CIDX),
                                               (const unsigned long long*)(ws + W_CKEY),
                                               ws + W_R4, ws + W_RS, (int*)(ws + W_VS));
    k5_mat<<<dim3(NW, BATCH), 64, 0, stream>>>(ws + W_RS, (unsigned long long*)(ws + W_MAT));
    k5_scan<<<BATCH, 64, 0, stream>>>((const unsigned long long*)(ws + W_MAT),
                                      ws + W_RS, (const int*)(ws + W_VS), out);
}

// Round 4
// 1720.712 us; speedup vs baseline: 2.2482x; 1.4430x over previous
//
#include <hip/hip_runtime.h>
#include <cstdint>
#include <cmath>

// ---------------- constants ----------------
namespace {
constexpr int BATCH = 4;
constexpr int CIN   = 512;
constexpr int CMID  = 512;
constexpr int HSZ   = 64, WSZ = 64, HWP = 4096;
constexpr int NA    = 36864;          // HW * 9 anchors
constexpr int NIN_  = 6000;
constexpr int NOUT2 = 300;
constexpr int NW    = 94;             // ceil(6000/64) u64 words per bitmask row

// d_out layout (float offsets)
constexpr size_t O_SC  = 0;           // rpn_scores (4,36864,2)
constexpr size_t O_LC  = 294912;      // rpn_locs   (4,36864,4)
constexpr size_t O_ROI = 884736;      // rois       (1200,4)
constexpr size_t O_IDX = 889536;      // roi_indices(1200)
constexpr size_t O_ANC = 890736;      // anchors    (36864,4)

// d_ws layout (float offsets). Phase A: h + w-split. Phase B (post-K2) aliases h.
// High-water = 10747904 floats = 43.0 MB (same as the proven R1-R3 layout).
constexpr size_t W_H    = 0;          // 8388608 floats (conv hidden, NCHW)
constexpr size_t W_WHI  = 8388608;    // 2359296 f16 (= 1179648 floats) W hi, [kk][co][ci]
constexpr size_t W_WLO  = 9568256;    // 2359296 f16 W lo (scaled 2048)
constexpr size_t W_R4   = 0;          // 589824  rois per anchor (aliases h: used after K2 only)
constexpr size_t W_SK   = 589824;     // 147456  score keys (fg or -inf)
constexpr size_t W_HIST = 737280;     // 16384 ints (4 x 4096 bins)
constexpr size_t W_CNT  = 753664;     // 4 ints
constexpr size_t W_CUT  = 753668;     // 4 ints (pad to 753728)
constexpr size_t W_CIDX = 753728;     // 147456 ints  candidate anchor idx
constexpr size_t W_CKEY = 901184;     // 294912 floats = 147456 u64 keys (8B aligned)
constexpr size_t W_RS   = 1196096;    // 96000  sorted rois (4,6000,4)
constexpr size_t W_VS   = 1292096;    // 24000 ints sorted validity
constexpr size_t W_MAT  = 1316096;    // 4*6000*94 u64 = 4512000 floats (suppression bits)
} // namespace

typedef _Float16 f16;
typedef __attribute__((ext_vector_type(4))) _Float16 f16x4;
typedef __attribute__((ext_vector_type(8))) _Float16 f16x8;
typedef __attribute__((ext_vector_type(4))) float f32x4;

// ---------------- K0w: split conv_w*64 into f16 hi/lo, layout [kk][co][ci] ----------------
__global__ __launch_bounds__(256) void k0w(const float* __restrict__ w,
                                           f16* __restrict__ whi, f16* __restrict__ wlo) {
    int o = blockIdx.x * 256 + threadIdx.x;     // 2359296 total
    int ci = o & 511;
    int r  = o >> 9;
    int co = r & 511;
    int kk = r >> 9;
    float f = w[(co * CIN + ci) * 9 + kk] * 64.0f;   // scale 64: keep hi out of f16-subnormals
    f16 hv = (f16)f;
    whi[o] = hv;
    wlo[o] = (f16)((f - (float)hv) * 2048.0f);       // lo scaled 2^11 into normal range
}

// ---------------- K1: 3x3 conv + bias + ReLU via f16-split MFMA (3 products) ----------
// 9-shift implicit GEMM. Block = 2 image rows x 128 co; wave = 1 row(64px) x 64 co.
// grid (32 row-pairs, 4 co-groups, 4 batch) = 512 blocks -> 2 blocks/CU. LDS 58.6 KB.
__global__ __launch_bounds__(256, 2) void k1_mfma(const float* __restrict__ x,
                                                  const f16* __restrict__ gwh,
                                                  const f16* __restrict__ gwl,
                                                  const float* __restrict__ bias,
                                                  float* __restrict__ h) {
    const int pt = blockIdx.x, cg = blockIdx.y, b = blockIdx.z;
    const int y0 = pt * 2, co0 = cg * 128;
    const int t = threadIdx.x;
    const int wave = t >> 6, lane = t & 63;
    const int wrow = wave >> 1, wco = wave & 1;
    const int m = lane & 15, q = lane >> 4;

    // X tile: [hi/lo][(row*66 + col)*40 + ci]  (rows y0-1..y0+2, cols = img_x+1, ci 0..31, pad to 40)
    __shared__ __align__(16) f16 xs[2][4 * 66 * 40];
    // W tile: [slot][hi/lo][co*32 + ci]
    __shared__ __align__(16) f16 wt[2][2][128 * 32];

    f32x4 acc1[4][4], acc2[4][4];
#pragma unroll
    for (int i = 0; i < 4; ++i)
#pragma unroll
        for (int j = 0; j < 4; ++j) { acc1[i][j] = (f32x4)0.0f; acc2[i][j] = (f32x4)0.0f; }

    // X staging roles
    const int cq = t & 7, srow = (t >> 3) & 3, cseg = t >> 5;
    const int gy = y0 - 1 + srow;
    const bool yok = (gy >= 0 && gy < HSZ);

    // zero the padding columns (img_x = -1 -> col 0, img_x = 64 -> col 65); never rewritten
    if (t < 128) {
        int buf = t >> 6, rr = (t >> 4) & 3, cc = ((t >> 3) & 1) ? 65 : 0, cq2 = t & 7;
        f16x4 z = (f16x4)(f16)0.0f;
        *(f16x4*)&xs[buf][(rr * 66 + cc) * 40 + cq2 * 4] = z;
    }

    // stage W for ks=0 into slot 0
    {
#pragma unroll
        for (int s = 0; s < 2; ++s) {
            int idx = s * 256 + t;               // 512 tasks of 8 f16
            int co_l = idx >> 2, q8 = idx & 3;
            size_t g = ((size_t)(co0 + co_l)) * 512 + q8 * 8;   // kk=0, chunk=0
            *(f16x8*)&wt[0][0][co_l * 32 + q8 * 8] = *(const f16x8*)&gwh[g];
            *(f16x8*)&wt[0][1][co_l * 32 + q8 * 8] = *(const f16x8*)&gwl[g];
        }
    }

    int chunk = 0, kk = 0;
    for (int ks = 0; ks < 144; ++ks) {
        const int slot = ks & 1;
        __syncthreads();   // all waves done with ks-1 compute -> safe to overwrite slot^1 and (if kk==0) X

        if (kk == 0) {
            // stage X(chunk): thread = (cq, srow, cseg); 4 ci x 8 cols
            float vb[4][8];
            const float* xp = x + ((size_t)(b * CIN + chunk * 32 + cq * 4)) * HWP + gy * WSZ + cseg * 8;
#pragma unroll
            for (int i = 0; i < 4; ++i) {
                if (yok) {
                    float4 u0 = *(const float4*)(xp + (size_t)i * HWP);
                    float4 u1 = *(const float4*)(xp + (size_t)i * HWP + 4);
                    vb[i][0] = u0.x; vb[i][1] = u0.y; vb[i][2] = u0.z; vb[i][3] = u0.w;
                    vb[i][4] = u1.x; vb[i][5] = u1.y; vb[i][6] = u1.z; vb[i][7] = u1.w;
                } else {
#pragma unroll
                    for (int jj = 0; jj < 8; ++jj) vb[i][jj] = 0.0f;
                }
            }
#pragma unroll
            for (int j = 0; j < 8; ++j) {
                int c = (j + cq) & 7;            // k-rotation: spread LDS banks across lanes
                int col = cseg * 8 + c + 1;
                f16x4 hv, lv;
#pragma unroll
                for (int i = 0; i < 4; ++i) {
                    float f = vb[i][c];
                    f16 hf = (f16)f;
                    hv[i] = hf;
                    lv[i] = (f16)((f - (float)hf) * 2048.0f);
                }
                int base = (srow * 66 + col) * 40 + cq * 4;
                *(f16x4*)&xs[0][base] = hv;
                *(f16x4*)&xs[1][base] = lv;
            }
        }

        // prefetch-stage W(ks+1) into slot^1 (overlaps compute; consumed next iter)
        if (ks + 1 < 144) {
            int kk2 = kk + 1, ch2 = chunk;
            if (kk2 == 9) { kk2 = 0; ch2++; }
#pragma unroll
            for (int s = 0; s < 2; ++s) {
                int idx = s * 256 + t;
                int co_l = idx >> 2, q8 = idx & 3;
                size_t g = ((size_t)(kk2 * 512 + co0 + co_l)) * 512 + ch2 * 32 + q8 * 8;
                *(f16x8*)&wt[slot ^ 1][0][co_l * 32 + q8 * 8] = *(const f16x8*)&gwh[g];
                *(f16x8*)&wt[slot ^ 1][1][co_l * 32 + q8 * 8] = *(const f16x8*)&gwl[g];
            }
        }

        if (kk == 0) __syncthreads();   // X(chunk) (and prologue W0) ready

        // compute shift kk with W[slot]
        const int ky = (kk >= 6) ? 2 : (kk >= 3) ? 1 : 0;
        const int kx = kk - ky * 3;
        const int rs = wrow + ky;

        f16x8 bh[4], bl[4], ah[4], al[4];
#pragma unroll
        for (int nt = 0; nt < 4; ++nt) {
            int off = (wco * 64 + nt * 16 + m) * 32 + q * 8;
            bh[nt] = *(const f16x8*)&wt[slot][0][off];
            bl[nt] = *(const f16x8*)&wt[slot][1][off];
        }
#pragma unroll
        for (int ct = 0; ct < 4; ++ct) {
            int off = (rs * 66 + ct * 16 + m + kx) * 40 + q * 8;
            ah[ct] = *(const f16x8*)&xs[0][off];
            al[ct] = *(const f16x8*)&xs[1][off];
        }
#pragma unroll
        for (int ct = 0; ct < 4; ++ct)
#pragma unroll
            for (int nt = 0; nt < 4; ++nt) {
                acc1[ct][nt] = __builtin_amdgcn_mfma_f32_16x16x32_f16(ah[ct], bh[nt], acc1[ct][nt], 0, 0, 0);
                acc2[ct][nt] = __builtin_amdgcn_mfma_f32_16x16x32_f16(ah[ct], bl[nt], acc2[ct][nt], 0, 0, 0);
                acc2[ct][nt] = __builtin_amdgcn_mfma_f32_16x16x32_f16(al[ct], bh[nt], acc2[ct][nt], 0, 0, 0);
            }

        ++kk;
        if (kk == 9) { kk = 0; ++chunk; }
    }

    // epilogue: h = (acc1 + acc2*2^-11)*2^-6 + bias, relu
    const int y = y0 + wrow;
#pragma unroll
    for (int nt = 0; nt < 4; ++nt) {
        const int co = co0 + wco * 64 + nt * 16 + m;    // D: n = lane&15
        const float bv = bias[co];
        size_t rowbase = ((size_t)(b * CMID + co)) * HWP + y * WSZ;
#pragma unroll
        for (int ct = 0; ct < 4; ++ct) {
            float4 o;
            o.x = fmaxf((acc1[ct][nt][0] + acc2[ct][nt][0] * (1.0f / 2048.0f)) * (1.0f / 64.0f) + bv, 0.0f);
            o.y = fmaxf((acc1[ct][nt][1] + acc2[ct][nt][1] * (1.0f / 2048.0f)) * (1.0f / 64.0f) + bv, 0.0f);
            o.z = fmaxf((acc1[ct][nt][2] + acc2[ct][nt][2] * (1.0f / 2048.0f)) * (1.0f / 64.0f) + bv, 0.0f);
            o.w = fmaxf((acc1[ct][nt][3] + acc2[ct][nt][3] * (1.0f / 2048.0f)) * (1.0f / 64.0f) + bv, 0.0f);
            *(float4*)&h[rowbase + ct * 16 + q * 4] = o;   // D: m = q*4+reg -> img x
        }
    }
}

// ---------------- K2: 1x1 convs (score 18 + loc 36) -> d_out in NHWC-anchor layout ----------
// grid (64 rows, 4 batch); block 256; thread = 4 channels x 4 px
__global__ __launch_bounds__(256) void k2_conv1(const float* __restrict__ h,
                                                const float* __restrict__ sw,
                                                const float* __restrict__ sb,
                                                const float* __restrict__ lw,
                                                const float* __restrict__ lb,
                                                float* __restrict__ out) {
    const int y = blockIdx.x;
    const int b = blockIdx.y;
    const int t = threadIdx.x;
    const int c4  = (t & 15) * 4;
    const int px4 = (t >> 4) * 4;
    __shared__ __align__(16) float hs[1024];        // [ci(16)][px(64)]
    __shared__ __align__(16) float wsm[16 * 68];    // [ci][c] padded

    float acc[4][4];
#pragma unroll
    for (int i = 0; i < 4; ++i)
#pragma unroll
        for (int j = 0; j < 4; ++j) acc[i][j] = 0.f;

    const int s_px = (t & 15) * 4;
    const int s_ci = t >> 4;
    for (int ci0 = 0; ci0 < CMID; ci0 += 16) {
        *(float4*)&hs[s_ci * 64 + s_px] =
            *(const float4*)&h[((size_t)(b * CMID + ci0 + s_ci)) * HWP + y * 64 + s_px];
#pragma unroll
        for (int k = 0; k < 4; ++k) {
            int idx = k * 256 + t;
            int ci = idx & 15, c = idx >> 4;
            float v = 0.f;
            if (c < 18) v = sw[c * 512 + ci0 + ci];
            else if (c < 54) v = lw[(c - 18) * 512 + ci0 + ci];
            wsm[ci * 68 + c] = v;
        }
        __syncthreads();
#pragma unroll
        for (int ci = 0; ci < 16; ++ci) {
            float4 hv = *(const float4*)&hs[ci * 64 + px4];
            float4 wv = *(const float4*)&wsm[ci * 68 + c4];
            acc[0][0] = fmaf(wv.x, hv.x, acc[0][0]);
            acc[0][1] = fmaf(wv.x, hv.y, acc[0][1]);
            acc[0][2] = fmaf(wv.x, hv.z, acc[0][2]);
            acc[0][3] = fmaf(wv.x, hv.w, acc[0][3]);
            acc[1][0] = fmaf(wv.y, hv.x, acc[1][0]);
            acc[1][1] = fmaf(wv.y, hv.y, acc[1][1]);
            acc[1][2] = fmaf(wv.y, hv.z, acc[1][2]);
            acc[1][3] = fmaf(wv.y, hv.w, acc[1][3]);
            acc[2][0] = fmaf(wv.z, hv.x, acc[2][0]);
            acc[2][1] = fmaf(wv.z, hv.y, acc[2][1]);
            acc[2][2] = fmaf(wv.z, hv.z, acc[2][2]);
            acc[2][3] = fmaf(wv.z, hv.w, acc[2][3]);
            acc[3][0] = fmaf(wv.w, hv.x, acc[3][0]);
            acc[3][1] = fmaf(wv.w, hv.y, acc[3][1]);
            acc[3][2] = fmaf(wv.w, hv.z, acc[3][2]);
            acc[3][3] = fmaf(wv.w, hv.w, acc[3][3]);
        }
        __syncthreads();
    }

#pragma unroll
    for (int cc = 0; cc < 4; ++cc) {
        int c = c4 + cc;
        if (c >= 54) break;
        float bv = (c < 18) ? sb[c] : lb[c - 18];
#pragma unroll
        for (int pp = 0; pp < 4; ++pp) {
            int px = y * 64 + px4 + pp;
            float v = acc[cc][pp] + bv;
            if (c < 18)
                out[O_SC + (size_t)b * 73728 + (size_t)px * 18 + c] = v;
            else
                out[O_LC + (size_t)b * 147456 + (size_t)px * 36 + (c - 18)] = v;
        }
    }
}

// ---------------- K3: anchors + softmax-fg + loc2bbox + clip + histogram ----------------
// grid (144, 4); block 256 -> one thread per anchor
__global__ __launch_bounds__(256) void k3_prop(float* __restrict__ out,
                                               float* __restrict__ rois4,
                                               float* __restrict__ skey,
                                               int* __restrict__ hist) {
    __shared__ int lh[4096];
    const int t = threadIdx.x;
    for (int k = t; k < 4096; k += 256) lh[k] = 0;
    __syncthreads();

    const int p = blockIdx.x * 256 + t;
    const int b = blockIdx.y;
    const int px = p / 9;
    const int a  = p - px * 9;
    const int yy = px >> 6, xx = px & 63;
    const int ri = a / 3, si = a - ri * 3;
    const double rat[3] = {0.5, 1.0, 2.0};
    const double scl[3] = {8.0, 16.0, 32.0};
    double hhd = 16.0 * scl[si] * sqrt(rat[ri]);
    double wwd = 16.0 * scl[si] * sqrt(1.0 / rat[ri]);
    float a0 = (float)(8.0 - hhd / 2.0), a1 = (float)(8.0 - wwd / 2.0);
    float a2 = (float)(8.0 + hhd / 2.0), a3 = (float)(8.0 + wwd / 2.0);
    float sy = (float)(yy * 16), sx = (float)(xx * 16);
    float A0 = sy + a0, A1 = sx + a1, A2 = sy + a2, A3 = sx + a3;
    if (b == 0) {
        float4 av; av.x = A0; av.y = A1; av.z = A2; av.w = A3;
        *(float4*)&out[O_ANC + (size_t)p * 4] = av;
    }
    const float* sc = out + O_SC + (size_t)b * 73728 + (size_t)px * 18 + a * 2;
    float s0 = sc[0], s1 = sc[1];
    float m = fmaxf(s0, s1);
    float e0 = expf(s0 - m), e1 = expf(s1 - m);
    float fg = e1 / (e0 + e1);
    const float* lc = out + O_LC + (size_t)b * 147456 + (size_t)px * 36 + a * 4;
    float dy = lc[0], dxv = lc[1], dh = lc[2], dwv = lc[3];
    float ah = A2 - A0, aw = A3 - A1;
    float cy = A0 + 0.5f * ah, cx = A1 + 0.5f * aw;
    float cty = dy * ah + cy, ctx = dxv * aw + cx;
    float th = expf(dh) * ah, tw = expf(dwv) * aw;
    float ry1 = cty - 0.5f * th, rx1 = ctx - 0.5f * tw;
    float ry2 = cty + 0.5f * th, rx2 = ctx + 0.5f * tw;
    float y1 = fminf(fmaxf(ry1, 0.f), 1024.f);
    float y2 = fminf(fmaxf(ry2, 0.f), 1024.f);
    float x1 = fminf(fmaxf(rx1, 0.f), 1024.f);
    float x2 = fminf(fmaxf(rx2, 0.f), 1024.f);
    bool valid = ((y2 - y1) >= 16.f) && ((x2 - x1) >= 16.f);
    float sk = valid ? fg : -__builtin_inff();
    float4 rv; rv.x = y1; rv.y = x1; rv.z = y2; rv.w = x2;
    *(float4*)&rois4[((size_t)b * NA + p) * 4] = rv;
    skey[(size_t)b * NA + p] = sk;
    unsigned u = __float_as_uint(sk);
    u = (u & 0x80000000u) ? ~u : (u | 0x80000000u);
    atomicAdd(&lh[u >> 20], 1);
    __syncthreads();
    for (int k = t; k < 4096; k += 256) {
        int v = lh[k];
        if (v) atomicAdd(&hist[b * 4096 + k], v);
    }
}

// ---------------- K4b: find cutoff bin (suffix count >= 6000) ----------------
__global__ __launch_bounds__(256) void k4b_scan(const int* __restrict__ hist,
                                                int* __restrict__ cut) {
    __shared__ int hl[4096];
    __shared__ int tsum[256];
    const int t = threadIdx.x;
    for (int b = 0; b < BATCH; ++b) {
        for (int k = t; k < 4096; k += 256) hl[k] = hist[b * 4096 + k];
        __syncthreads();
        int s = 0;
#pragma unroll
        for (int j = 0; j < 16; ++j) s += hl[t * 16 + j];
        tsum[t] = s;
        __syncthreads();
        if (t == 0) {
            int run = 0;
            for (int tt = 255; tt >= 0; --tt) { int tmp = tsum[tt]; tsum[tt] = run; run += tmp; }
        }
        __syncthreads();
        int run = tsum[t];
        for (int v = t * 16 + 15; v >= t * 16; --v) {
            int prev = run;
            run += hl[v];
            if (run >= NIN_ && prev < NIN_) cut[b] = v;
        }
        __syncthreads();
    }
}

// ---------------- K4c: compact candidates (bin >= cut) ----------------
__global__ __launch_bounds__(256) void k4c_compact(const float* __restrict__ skey,
                                                   const int* __restrict__ cut,
                                                   int* __restrict__ cnt,
                                                   int* __restrict__ cidx,
                                                   unsigned long long* __restrict__ ckey) {
    const int p = blockIdx.x * 256 + threadIdx.x;
    const int b = blockIdx.y;
    float sk = skey[(size_t)b * NA + p];
    unsigned u = __float_as_uint(sk);
    u = (u & 0x80000000u) ? ~u : (u | 0x80000000u);
    if ((int)(u >> 20) >= cut[b]) {
        int pos = atomicAdd(&cnt[b], 1);
        cidx[(size_t)b * NA + pos] = p;
        // 48-bit key: score bits (monotone) then inverted index -> unique, matches
        // stable argsort(-s) tie-breaking (lower index wins on equal score)
        ckey[(size_t)b * NA + pos] =
            ((unsigned long long)u << 16) | (unsigned long long)(36863 - p);
    }
}

// ---------------- K4d: exact rank among candidates + scatter sorted top-6000 ----------------
__global__ __launch_bounds__(256) void k4d_rank(const int* __restrict__ cnt,
                                                const int* __restrict__ cidx,
                                                const unsigned long long* __restrict__ ckey,
                                                const float* __restrict__ rois4,
                                                float* __restrict__ rois_s,
                                                int* __restrict__ valid_s) {
    const int b = blockIdx.y;
    const int C = cnt[b];
    if (blockIdx.x * 256 >= C) return;   // whole-block early exit (C uniform)
    const int gi = blockIdx.x * 256 + threadIdx.x;
    const bool act = gi < C;
    const unsigned long long mk = act ? ckey[(size_t)b * NA + gi] : 0ULL;
    __shared__ unsigned long long kl[512];
    int rank = 0;
    for (int c0 = 0; c0 < C; c0 += 512) {
        __syncthreads();
#pragma unroll
        for (int kk = 0; kk < 2; ++kk) {
            int k = threadIdx.x + kk * 256;
            int src = c0 + k;
            kl[k] = (src < C) ? ckey[(size_t)b * NA + src] : 0ULL;
        }
        __syncthreads();
        if (act) {
            int n = min(512, C - c0);
            int j = 0;
            for (; j + 4 <= n; j += 4) {
                rank += (kl[j]     > mk);
                rank += (kl[j + 1] > mk);
                rank += (kl[j + 2] > mk);
                rank += (kl[j + 3] > mk);
            }
            for (; j < n; ++j) rank += (kl[j] > mk);
        }
    }
    if (act && rank < NIN_) {
        int src = cidx[(size_t)b * NA + gi];
        const float4 bx = *(const float4*)&rois4[((size_t)b * NA + src) * 4];
        *(float4*)&rois_s[((size_t)b * NIN_ + rank) * 4] = bx;
        valid_s[(size_t)b * NIN_ + rank] = ((unsigned)(mk >> 16) != 0x007FFFFFu) ? 1 : 0;
    }
}

// ---------------- K5a: pairwise suppression bitmask matrix ----------------
// grid (94 rowblocks, 4 batch); block 64 (one wave); thread = row i.
__global__ __launch_bounds__(64) void k5_mat(const float* __restrict__ rois_s,
                                             unsigned long long* __restrict__ mat) {
    const int b = blockIdx.y, t = threadIdx.x;
    const int i = blockIdx.x * 64 + t;
    __shared__ float cy1[64], cx1[64], cy2[64], cx2[64], car[64];
    const float* bb = rois_s + (size_t)b * NIN_ * 4;
    const bool rowok = (i < NIN_);
    float r0 = 0, r1 = 0, r2 = 0, r3 = 0, ra = 0;
    if (rowok) {
        float4 v = *(const float4*)&bb[(size_t)i * 4];
        r0 = v.x; r1 = v.y; r2 = v.z; r3 = v.w;
        ra = (v.z - v.x) * (v.w - v.y);
    }
    unsigned long long* mrow = mat + ((size_t)b * NIN_ + (rowok ? i : 0)) * NW;
    for (int cb = 0; cb < NW; ++cb) {
        const int j0 = cb * 64;
        const int j  = j0 + t;
        float4 v;
        if (j < NIN_) v = *(const float4*)&bb[(size_t)j * 4];
        else { v.x = 0; v.y = 0; v.z = 0; v.w = 0; }
        __syncthreads();
        cy1[t] = v.x; cx1[t] = v.y; cy2[t] = v.z; cx2[t] = v.w;
        car[t] = (v.z - v.x) * (v.w - v.y);
        __syncthreads();
        unsigned long long wm = 0;
        if (rowok && (j0 + 63 > i)) {
            const int kbeg = (i + 1 > j0) ? (i + 1 - j0) : 0;
            const int kend = (NIN_ - j0 < 64) ? (NIN_ - j0) : 64;
            for (int k = kbeg; k < kend; ++k) {
                float yy1 = fmaxf(r0, cy1[k]), xx1 = fmaxf(r1, cx1[k]);
                float yy2 = fminf(r2, cy2[k]), xx2 = fminf(r3, cx2[k]);
                float inter = fmaxf(yy2 - yy1, 0.f) * fmaxf(xx2 - xx1, 0.f);
                float iou = inter / (ra + car[k] - inter + 1e-9f);
                if (iou > 0.7f) wm |= (1ull << k);
            }
        }
        if (rowok) mrow[cb] = wm;
    }
}

// ---------------- K5b: serial greedy scan over bitmask ----------------
__global__ __launch_bounds__(64) void k5_scan(const unsigned long long* __restrict__ mat,
                                              const float* __restrict__ rois_s,
                                              const int* __restrict__ valid_s,
                                              float* __restrict__ out) {
    const int b = blockIdx.x, t = threadIdx.x;
    for (int k = t; k < NOUT2 * 4; k += 64) out[O_ROI + (size_t)b * NOUT2 * 4 + k] = 0.f;
    for (int k = t; k < NOUT2; k += 64) out[O_IDX + (size_t)b * NOUT2 + k] = (float)b;

    unsigned long long A = 0, B = 0;
    for (int w = 0; w < NW; ++w) {
        int i = w * 64 + t;
        int v = (i < NIN_) ? valid_s[b * NIN_ + i] : 0;
        unsigned long long m = __ballot(v == 0);
        if (w < 64) { if (t == w) A = m; }
        else        { if (t == w - 64) B = m; }
    }

    const unsigned long long* mb = mat + (size_t)b * NIN_ * NW;
    const float* bb = rois_s + (size_t)b * NIN_ * 4;
    int kept = 0;
    for (int w = 0; w < NW && kept < NOUT2; ++w) {
        unsigned long long cur = (w < 64) ? __shfl(A, w) : __shfl(B, w - 64);
        unsigned long long avail = ~cur;
        while (avail != 0ull && kept < NOUT2) {
            int bit = __builtin_ctzll(avail);
            int i = w * 64 + bit;
            if (t == 0) {
                float4 bx = *(const float4*)&bb[(size_t)i * 4];
                *(float4*)&out[O_ROI + ((size_t)b * NOUT2 + kept) * 4] = bx;
            }
            kept++;
            if (kept >= NOUT2) break;
            const unsigned long long* row = mb + (size_t)i * NW;
            unsigned long long rA = row[t];
            unsigned long long rB = (t < NW - 64) ? row[64 + t] : 0ull;
            A |= rA; B |= rB;
            unsigned long long rw = (w < 64) ? __shfl(rA, w) : __shfl(rB, w - 64);
            avail &= ~rw;
            avail &= ~(1ull << bit);
        }
    }
}

// ---------------- launch ----------------
extern "C" void kernel_launch(void* const* d_in, const int* in_sizes, int n_in,
                              void* d_out, int out_size, void* d_ws, size_t ws_size,
                              hipStream_t stream) {
    const float* x       = (const float*)d_in[0];
    const float* conv_w  = (const float*)d_in[1];
    const float* conv_b  = (const float*)d_in[2];
    const float* score_w = (const float*)d_in[3];
    const float* score_b = (const float*)d_in[4];
    const float* loc_w   = (const float*)d_in[5];
    const float* loc_b   = (const float*)d_in[6];
    float* out = (float*)d_out;
    float* ws  = (float*)d_ws;    // high-water 43.0 MB (same as R1-R3)

    f16* whi = (f16*)(ws + W_WHI);
    f16* wlo = (f16*)(ws + W_WLO);

    k0w<<<2359296 / 256, 256, 0, stream>>>(conv_w, whi, wlo);
    k1_mfma<<<dim3(32, 4, 4), 256, 0, stream>>>(x, whi, wlo, conv_b, ws + W_H);
    k2_conv1<<<dim3(64, 4), 256, 0, stream>>>(ws + W_H, score_w, score_b, loc_w, loc_b, out);
    // zero hist + cnt + cut (region aliases h, so zero AFTER K2 is done with h)
    hipMemsetAsync(ws + W_HIST, 0, (size_t)16448 * 4, stream);
    k3_prop<<<dim3(144, 4), 256, 0, stream>>>(out, ws + W_R4, ws + W_SK, (int*)(ws + W_HIST));
    k4b_scan<<<1, 256, 0, stream>>>((const int*)(ws + W_HIST), (int*)(ws + W_CUT));
    k4c_compact<<<dim3(144, 4), 256, 0, stream>>>(ws + W_SK, (const int*)(ws + W_CUT),
                                                  (int*)(ws + W_CNT), (int*)(ws + W_CIDX),
                                                  (unsigned long long*)(ws + W_CKEY));
    k4d_rank<<<dim3(144, 4), 256, 0, stream>>>((const int*)(ws + W_CNT), (const int*)(ws + W_CIDX),
                                               (const unsigned long long*)(ws + W_CKEY),
                                               ws + W_R4, ws + W_RS, (int*)(ws + W_VS));
    k5_mat<<<dim3(NW, BATCH), 64, 0, stream>>>(ws + W_RS, (unsigned long long*)(ws + W_MAT));
    k5_scan<<<BATCH, 64, 0, stream>>>((const unsigned long long*)(ws + W_MAT),
                                      ws + W_RS, (const int*)(ws + W_VS), out);
}

// Round 5
// 1241.754 us; speedup vs baseline: 3.1154x; 1.3857x over previous
//
#include <hip/hip_runtime.h>
#include <cstdint>
#include <cmath>

// ---------------- constants ----------------
namespace {
constexpr int BATCH = 4;
constexpr int CIN   = 512;
constexpr int CMID  = 512;
constexpr int HSZ   = 64, WSZ = 64, HWP = 4096;
constexpr int NA    = 36864;          // HW * 9 anchors
constexpr int NIN_  = 6000;
constexpr int NOUT2 = 300;
constexpr int NW    = 94;             // ceil(6000/64) u64 words per bitmask row

// d_out layout (float offsets)
constexpr size_t O_SC  = 0;           // rpn_scores (4,36864,2)
constexpr size_t O_LC  = 294912;      // rpn_locs   (4,36864,4)
constexpr size_t O_ROI = 884736;      // rois       (1200,4)
constexpr size_t O_IDX = 889536;      // roi_indices(1200)
constexpr size_t O_ANC = 890736;      // anchors    (36864,4)

// d_ws layout (float offsets). Phase A: h + w-split. Phase B (post-K2) aliases h.
// High-water = 10747904 floats = 43.0 MB (same as the proven R1-R4 layout).
constexpr size_t W_H    = 0;          // 8388608 floats (conv hidden, NCHW)
constexpr size_t W_WHI  = 8388608;    // 2359296 f16 (= 1179648 floats) W hi, [kk][co][ci]
constexpr size_t W_WLO  = 9568256;    // 2359296 f16 W lo (scaled 2048)
constexpr size_t W_R4   = 0;          // 589824  rois per anchor (aliases h: used after K2 only)
constexpr size_t W_SK   = 589824;     // 147456  score keys (fg or -inf)
constexpr size_t W_HIST = 737280;     // 16384 ints (4 x 4096 bins)
constexpr size_t W_CNT  = 753664;     // 4 ints
constexpr size_t W_CUT  = 753668;     // 4 ints (pad to 753728)
constexpr size_t W_CIDX = 753728;     // 147456 ints  candidate anchor idx
constexpr size_t W_CKEY = 901184;     // 294912 floats = 147456 u64 keys (8B aligned)
constexpr size_t W_RS   = 1196096;    // 96000  sorted rois (4,6000,4)
constexpr size_t W_VS   = 1292096;    // 24000 ints sorted validity
constexpr size_t W_MAT  = 1316096;    // 4*6000*94 u64 = 4512000 floats (suppression bits)
} // namespace

typedef _Float16 f16;
typedef __attribute__((ext_vector_type(4))) _Float16 f16x4;
typedef __attribute__((ext_vector_type(8))) _Float16 f16x8;
typedef __attribute__((ext_vector_type(4))) float f32x4;

// ---------------- K0w: split conv_w*64 into f16 hi/lo, layout [kk][co][ci] ----------------
__global__ __launch_bounds__(256) void k0w(const float* __restrict__ w,
                                           f16* __restrict__ whi, f16* __restrict__ wlo) {
    int o = blockIdx.x * 256 + threadIdx.x;     // 2359296 total
    int ci = o & 511;
    int r  = o >> 9;
    int co = r & 511;
    int kk = r >> 9;
    float f = w[(co * CIN + ci) * 9 + kk] * 64.0f;   // scale 64: keep hi out of f16-subnormals
    f16 hv = (f16)f;
    whi[o] = hv;
    wlo[o] = (f16)((f - (float)hv) * 2048.0f);       // lo scaled 2^11 into normal range
}

// ---------------- K1: 3x3 conv + bias + ReLU via f16-split MFMA (3 products) ----------
// 9-shift implicit GEMM. Block = 2 image rows x 128 co; wave = 1 row(64px) x 64 co.
// grid (32 row-pairs, 4 co-groups, 4 batch) = 512 blocks -> 2 blocks/CU. LDS 58.6 KB.
__global__ __launch_bounds__(256, 2) void k1_mfma(const float* __restrict__ x,
                                                  const f16* __restrict__ gwh,
                                                  const f16* __restrict__ gwl,
                                                  const float* __restrict__ bias,
                                                  float* __restrict__ h) {
    const int pt = blockIdx.x, cg = blockIdx.y, b = blockIdx.z;
    const int y0 = pt * 2, co0 = cg * 128;
    const int t = threadIdx.x;
    const int wave = t >> 6, lane = t & 63;
    const int wrow = wave >> 1, wco = wave & 1;
    const int m = lane & 15, q = lane >> 4;

    // X tile: [hi/lo][(row*66 + col)*40 + ci]  (rows y0-1..y0+2, cols = img_x+1, ci 0..31, pad to 40)
    __shared__ __align__(16) f16 xs[2][4 * 66 * 40];
    // W tile: [slot][hi/lo][co*32 + ci]
    __shared__ __align__(16) f16 wt[2][2][128 * 32];

    f32x4 acc1[4][4], acc2[4][4];
#pragma unroll
    for (int i = 0; i < 4; ++i)
#pragma unroll
        for (int j = 0; j < 4; ++j) { acc1[i][j] = (f32x4)0.0f; acc2[i][j] = (f32x4)0.0f; }

    // X staging roles
    const int cq = t & 7, srow = (t >> 3) & 3, cseg = t >> 5;
    const int gy = y0 - 1 + srow;
    const bool yok = (gy >= 0 && gy < HSZ);

    // zero the padding columns (img_x = -1 -> col 0, img_x = 64 -> col 65); never rewritten
    if (t < 128) {
        int buf = t >> 6, rr = (t >> 4) & 3, cc = ((t >> 3) & 1) ? 65 : 0, cq2 = t & 7;
        f16x4 z = (f16x4)(f16)0.0f;
        *(f16x4*)&xs[buf][(rr * 66 + cc) * 40 + cq2 * 4] = z;
    }

    // stage W for ks=0 into slot 0
    {
#pragma unroll
        for (int s = 0; s < 2; ++s) {
            int idx = s * 256 + t;               // 512 tasks of 8 f16
            int co_l = idx >> 2, q8 = idx & 3;
            size_t g = ((size_t)(co0 + co_l)) * 512 + q8 * 8;   // kk=0, chunk=0
            *(f16x8*)&wt[0][0][co_l * 32 + q8 * 8] = *(const f16x8*)&gwh[g];
            *(f16x8*)&wt[0][1][co_l * 32 + q8 * 8] = *(const f16x8*)&gwl[g];
        }
    }

    int chunk = 0, kk = 0;
    for (int ks = 0; ks < 144; ++ks) {
        const int slot = ks & 1;
        __syncthreads();   // all waves done with ks-1 compute -> safe to overwrite slot^1 and (if kk==0) X

        if (kk == 0) {
            // stage X(chunk): thread = (cq, srow, cseg); 4 ci x 8 cols
            float vb[4][8];
            const float* xp = x + ((size_t)(b * CIN + chunk * 32 + cq * 4)) * HWP + gy * WSZ + cseg * 8;
#pragma unroll
            for (int i = 0; i < 4; ++i) {
                if (yok) {
                    float4 u0 = *(const float4*)(xp + (size_t)i * HWP);
                    float4 u1 = *(const float4*)(xp + (size_t)i * HWP + 4);
                    vb[i][0] = u0.x; vb[i][1] = u0.y; vb[i][2] = u0.z; vb[i][3] = u0.w;
                    vb[i][4] = u1.x; vb[i][5] = u1.y; vb[i][6] = u1.z; vb[i][7] = u1.w;
                } else {
#pragma unroll
                    for (int jj = 0; jj < 8; ++jj) vb[i][jj] = 0.0f;
                }
            }
#pragma unroll
            for (int j = 0; j < 8; ++j) {
                int c = (j + cq) & 7;            // k-rotation: spread LDS banks across lanes
                int col = cseg * 8 + c + 1;
                f16x4 hv, lv;
#pragma unroll
                for (int i = 0; i < 4; ++i) {
                    float f = vb[i][c];
                    f16 hf = (f16)f;
                    hv[i] = hf;
                    lv[i] = (f16)((f - (float)hf) * 2048.0f);
                }
                int base = (srow * 66 + col) * 40 + cq * 4;
                *(f16x4*)&xs[0][base] = hv;
                *(f16x4*)&xs[1][base] = lv;
            }
        }

        // prefetch-stage W(ks+1) into slot^1 (overlaps compute; consumed next iter)
        if (ks + 1 < 144) {
            int kk2 = kk + 1, ch2 = chunk;
            if (kk2 == 9) { kk2 = 0; ch2++; }
#pragma unroll
            for (int s = 0; s < 2; ++s) {
                int idx = s * 256 + t;
                int co_l = idx >> 2, q8 = idx & 3;
                size_t g = ((size_t)(kk2 * 512 + co0 + co_l)) * 512 + ch2 * 32 + q8 * 8;
                *(f16x8*)&wt[slot ^ 1][0][co_l * 32 + q8 * 8] = *(const f16x8*)&gwh[g];
                *(f16x8*)&wt[slot ^ 1][1][co_l * 32 + q8 * 8] = *(const f16x8*)&gwl[g];
            }
        }

        if (kk == 0) __syncthreads();   // X(chunk) (and prologue W0) ready

        // compute shift kk with W[slot]
        const int ky = (kk >= 6) ? 2 : (kk >= 3) ? 1 : 0;
        const int kx = kk - ky * 3;
        const int rs = wrow + ky;

        f16x8 bh[4], bl[4], ah[4], al[4];
#pragma unroll
        for (int nt = 0; nt < 4; ++nt) {
            int off = (wco * 64 + nt * 16 + m) * 32 + q * 8;
            bh[nt] = *(const f16x8*)&wt[slot][0][off];
            bl[nt] = *(const f16x8*)&wt[slot][1][off];
        }
#pragma unroll
        for (int ct = 0; ct < 4; ++ct) {
            int off = (rs * 66 + ct * 16 + m + kx) * 40 + q * 8;
            ah[ct] = *(const f16x8*)&xs[0][off];
            al[ct] = *(const f16x8*)&xs[1][off];
        }
#pragma unroll
        for (int ct = 0; ct < 4; ++ct)
#pragma unroll
            for (int nt = 0; nt < 4; ++nt) {
                acc1[ct][nt] = __builtin_amdgcn_mfma_f32_16x16x32_f16(ah[ct], bh[nt], acc1[ct][nt], 0, 0, 0);
                acc2[ct][nt] = __builtin_amdgcn_mfma_f32_16x16x32_f16(ah[ct], bl[nt], acc2[ct][nt], 0, 0, 0);
                acc2[ct][nt] = __builtin_amdgcn_mfma_f32_16x16x32_f16(al[ct], bh[nt], acc2[ct][nt], 0, 0, 0);
            }

        ++kk;
        if (kk == 9) { kk = 0; ++chunk; }
    }

    // epilogue: h = (acc1 + acc2*2^-11)*2^-6 + bias, relu
    const int y = y0 + wrow;
#pragma unroll
    for (int nt = 0; nt < 4; ++nt) {
        const int co = co0 + wco * 64 + nt * 16 + m;    // D: n = lane&15
        const float bv = bias[co];
        size_t rowbase = ((size_t)(b * CMID + co)) * HWP + y * WSZ;
#pragma unroll
        for (int ct = 0; ct < 4; ++ct) {
            float4 o;
            o.x = fmaxf((acc1[ct][nt][0] + acc2[ct][nt][0] * (1.0f / 2048.0f)) * (1.0f / 64.0f) + bv, 0.0f);
            o.y = fmaxf((acc1[ct][nt][1] + acc2[ct][nt][1] * (1.0f / 2048.0f)) * (1.0f / 64.0f) + bv, 0.0f);
            o.z = fmaxf((acc1[ct][nt][2] + acc2[ct][nt][2] * (1.0f / 2048.0f)) * (1.0f / 64.0f) + bv, 0.0f);
            o.w = fmaxf((acc1[ct][nt][3] + acc2[ct][nt][3] * (1.0f / 2048.0f)) * (1.0f / 64.0f) + bv, 0.0f);
            *(float4*)&h[rowbase + ct * 16 + q * 4] = o;   // D: m = q*4+reg -> img x
        }
    }
}

// ---------------- K2: 1x1 convs (score 18 + loc 36) -> d_out in NHWC-anchor layout ----------
// grid (64 rows, 4 batch); block 256; thread = 4 channels x 4 px
__global__ __launch_bounds__(256) void k2_conv1(const float* __restrict__ h,
                                                const float* __restrict__ sw,
                                                const float* __restrict__ sb,
                                                const float* __restrict__ lw,
                                                const float* __restrict__ lb,
                                                float* __restrict__ out) {
    const int y = blockIdx.x;
    const int b = blockIdx.y;
    const int t = threadIdx.x;
    const int c4  = (t & 15) * 4;
    const int px4 = (t >> 4) * 4;
    __shared__ __align__(16) float hs[1024];        // [ci(16)][px(64)]
    __shared__ __align__(16) float wsm[16 * 68];    // [ci][c] padded

    float acc[4][4];
#pragma unroll
    for (int i = 0; i < 4; ++i)
#pragma unroll
        for (int j = 0; j < 4; ++j) acc[i][j] = 0.f;

    const int s_px = (t & 15) * 4;
    const int s_ci = t >> 4;
    for (int ci0 = 0; ci0 < CMID; ci0 += 16) {
        *(float4*)&hs[s_ci * 64 + s_px] =
            *(const float4*)&h[((size_t)(b * CMID + ci0 + s_ci)) * HWP + y * 64 + s_px];
#pragma unroll
        for (int k = 0; k < 4; ++k) {
            int idx = k * 256 + t;
            int ci = idx & 15, c = idx >> 4;
            float v = 0.f;
            if (c < 18) v = sw[c * 512 + ci0 + ci];
            else if (c < 54) v = lw[(c - 18) * 512 + ci0 + ci];
            wsm[ci * 68 + c] = v;
        }
        __syncthreads();
#pragma unroll
        for (int ci = 0; ci < 16; ++ci) {
            float4 hv = *(const float4*)&hs[ci * 64 + px4];
            float4 wv = *(const float4*)&wsm[ci * 68 + c4];
            acc[0][0] = fmaf(wv.x, hv.x, acc[0][0]);
            acc[0][1] = fmaf(wv.x, hv.y, acc[0][1]);
            acc[0][2] = fmaf(wv.x, hv.z, acc[0][2]);
            acc[0][3] = fmaf(wv.x, hv.w, acc[0][3]);
            acc[1][0] = fmaf(wv.y, hv.x, acc[1][0]);
            acc[1][1] = fmaf(wv.y, hv.y, acc[1][1]);
            acc[1][2] = fmaf(wv.y, hv.z, acc[1][2]);
            acc[1][3] = fmaf(wv.y, hv.w, acc[1][3]);
            acc[2][0] = fmaf(wv.z, hv.x, acc[2][0]);
            acc[2][1] = fmaf(wv.z, hv.y, acc[2][1]);
            acc[2][2] = fmaf(wv.z, hv.z, acc[2][2]);
            acc[2][3] = fmaf(wv.z, hv.w, acc[2][3]);
            acc[3][0] = fmaf(wv.w, hv.x, acc[3][0]);
            acc[3][1] = fmaf(wv.w, hv.y, acc[3][1]);
            acc[3][2] = fmaf(wv.w, hv.z, acc[3][2]);
            acc[3][3] = fmaf(wv.w, hv.w, acc[3][3]);
        }
        __syncthreads();
    }

#pragma unroll
    for (int cc = 0; cc < 4; ++cc) {
        int c = c4 + cc;
        if (c >= 54) break;
        float bv = (c < 18) ? sb[c] : lb[c - 18];
#pragma unroll
        for (int pp = 0; pp < 4; ++pp) {
            int px = y * 64 + px4 + pp;
            float v = acc[cc][pp] + bv;
            if (c < 18)
                out[O_SC + (size_t)b * 73728 + (size_t)px * 18 + c] = v;
            else
                out[O_LC + (size_t)b * 147456 + (size_t)px * 36 + (c - 18)] = v;
        }
    }
}

// ---------------- K3: anchors + softmax-fg + loc2bbox + clip + histogram ----------------
// grid (144, 4); block 256 -> one thread per anchor
__global__ __launch_bounds__(256) void k3_prop(float* __restrict__ out,
                                               float* __restrict__ rois4,
                                               float* __restrict__ skey,
                                               int* __restrict__ hist) {
    __shared__ int lh[4096];
    const int t = threadIdx.x;
    for (int k = t; k < 4096; k += 256) lh[k] = 0;
    __syncthreads();

    const int p = blockIdx.x * 256 + t;
    const int b = blockIdx.y;
    const int px = p / 9;
    const int a  = p - px * 9;
    const int yy = px >> 6, xx = px & 63;
    const int ri = a / 3, si = a - ri * 3;
    const double rat[3] = {0.5, 1.0, 2.0};
    const double scl[3] = {8.0, 16.0, 32.0};
    double hhd = 16.0 * scl[si] * sqrt(rat[ri]);
    double wwd = 16.0 * scl[si] * sqrt(1.0 / rat[ri]);
    float a0 = (float)(8.0 - hhd / 2.0), a1 = (float)(8.0 - wwd / 2.0);
    float a2 = (float)(8.0 + hhd / 2.0), a3 = (float)(8.0 + wwd / 2.0);
    float sy = (float)(yy * 16), sx = (float)(xx * 16);
    float A0 = sy + a0, A1 = sx + a1, A2 = sy + a2, A3 = sx + a3;
    if (b == 0) {
        float4 av; av.x = A0; av.y = A1; av.z = A2; av.w = A3;
        *(float4*)&out[O_ANC + (size_t)p * 4] = av;
    }
    const float* sc = out + O_SC + (size_t)b * 73728 + (size_t)px * 18 + a * 2;
    float s0 = sc[0], s1 = sc[1];
    float m = fmaxf(s0, s1);
    float e0 = expf(s0 - m), e1 = expf(s1 - m);
    float fg = e1 / (e0 + e1);
    const float* lc = out + O_LC + (size_t)b * 147456 + (size_t)px * 36 + a * 4;
    float dy = lc[0], dxv = lc[1], dh = lc[2], dwv = lc[3];
    float ah = A2 - A0, aw = A3 - A1;
    float cy = A0 + 0.5f * ah, cx = A1 + 0.5f * aw;
    float cty = dy * ah + cy, ctx = dxv * aw + cx;
    float th = expf(dh) * ah, tw = expf(dwv) * aw;
    float ry1 = cty - 0.5f * th, rx1 = ctx - 0.5f * tw;
    float ry2 = cty + 0.5f * th, rx2 = ctx + 0.5f * tw;
    float y1 = fminf(fmaxf(ry1, 0.f), 1024.f);
    float y2 = fminf(fmaxf(ry2, 0.f), 1024.f);
    float x1 = fminf(fmaxf(rx1, 0.f), 1024.f);
    float x2 = fminf(fmaxf(rx2, 0.f), 1024.f);
    bool valid = ((y2 - y1) >= 16.f) && ((x2 - x1) >= 16.f);
    float sk = valid ? fg : -__builtin_inff();
    float4 rv; rv.x = y1; rv.y = x1; rv.z = y2; rv.w = x2;
    *(float4*)&rois4[((size_t)b * NA + p) * 4] = rv;
    skey[(size_t)b * NA + p] = sk;
    unsigned u = __float_as_uint(sk);
    u = (u & 0x80000000u) ? ~u : (u | 0x80000000u);
    atomicAdd(&lh[u >> 20], 1);
    __syncthreads();
    for (int k = t; k < 4096; k += 256) {
        int v = lh[k];
        if (v) atomicAdd(&hist[b * 4096 + k], v);
    }
}

// ---------------- K4b: find cutoff bin (suffix count >= 6000) ----------------
__global__ __launch_bounds__(256) void k4b_scan(const int* __restrict__ hist,
                                                int* __restrict__ cut) {
    __shared__ int hl[4096];
    __shared__ int tsum[256];
    const int t = threadIdx.x;
    for (int b = 0; b < BATCH; ++b) {
        for (int k = t; k < 4096; k += 256) hl[k] = hist[b * 4096 + k];
        __syncthreads();
        int s = 0;
#pragma unroll
        for (int j = 0; j < 16; ++j) s += hl[t * 16 + j];
        tsum[t] = s;
        __syncthreads();
        if (t == 0) {
            int run = 0;
            for (int tt = 255; tt >= 0; --tt) { int tmp = tsum[tt]; tsum[tt] = run; run += tmp; }
        }
        __syncthreads();
        int run = tsum[t];
        for (int v = t * 16 + 15; v >= t * 16; --v) {
            int prev = run;
            run += hl[v];
            if (run >= NIN_ && prev < NIN_) cut[b] = v;
        }
        __syncthreads();
    }
}

// ---------------- K4c: compact candidates (bin >= cut) ----------------
__global__ __launch_bounds__(256) void k4c_compact(const float* __restrict__ skey,
                                                   const int* __restrict__ cut,
                                                   int* __restrict__ cnt,
                                                   int* __restrict__ cidx,
                                                   unsigned long long* __restrict__ ckey) {
    const int p = blockIdx.x * 256 + threadIdx.x;
    const int b = blockIdx.y;
    float sk = skey[(size_t)b * NA + p];
    unsigned u = __float_as_uint(sk);
    u = (u & 0x80000000u) ? ~u : (u | 0x80000000u);
    if ((int)(u >> 20) >= cut[b]) {
        int pos = atomicAdd(&cnt[b], 1);
        cidx[(size_t)b * NA + pos] = p;
        // 48-bit key: score bits (monotone) then inverted index -> unique, matches
        // stable argsort(-s) tie-breaking (lower index wins on equal score)
        ckey[(size_t)b * NA + pos] =
            ((unsigned long long)u << 16) | (unsigned long long)(36863 - p);
    }
}

// ---------------- K4d: exact rank among candidates + scatter sorted top-6000 ----------------
__global__ __launch_bounds__(256) void k4d_rank(const int* __restrict__ cnt,
                                                const int* __restrict__ cidx,
                                                const unsigned long long* __restrict__ ckey,
                                                const float* __restrict__ rois4,
                                                float* __restrict__ rois_s,
                                                int* __restrict__ valid_s) {
    const int b = blockIdx.y;
    const int C = cnt[b];
    if (blockIdx.x * 256 >= C) return;   // whole-block early exit (C uniform)
    const int gi = blockIdx.x * 256 + threadIdx.x;
    const bool act = gi < C;
    const unsigned long long mk = act ? ckey[(size_t)b * NA + gi] : 0ULL;
    __shared__ unsigned long long kl[512];
    int rank = 0;
    for (int c0 = 0; c0 < C; c0 += 512) {
        __syncthreads();
#pragma unroll
        for (int kk = 0; kk < 2; ++kk) {
            int k = threadIdx.x + kk * 256;
            int src = c0 + k;
            kl[k] = (src < C) ? ckey[(size_t)b * NA + src] : 0ULL;
        }
        __syncthreads();
        if (act) {
            int n = min(512, C - c0);
            int j = 0;
            for (; j + 4 <= n; j += 4) {
                rank += (kl[j]     > mk);
                rank += (kl[j + 1] > mk);
                rank += (kl[j + 2] > mk);
                rank += (kl[j + 3] > mk);
            }
            for (; j < n; ++j) rank += (kl[j] > mk);
        }
    }
    if (act && rank < NIN_) {
        int src = cidx[(size_t)b * NA + gi];
        const float4 bx = *(const float4*)&rois4[((size_t)b * NA + src) * 4];
        *(float4*)&rois_s[((size_t)b * NIN_ + rank) * 4] = bx;
        valid_s[(size_t)b * NIN_ + rank] = ((unsigned)(mk >> 16) != 0x007FFFFFu) ? 1 : 0;
    }
}

// ---------------- K5a: pairwise suppression bitmask matrix ----------------
// grid (94 rowblocks, 4 batch); block 256 = 4 waves, all on the same 64 rows.
// Waves split column-blocks (cb = rb+wave, step 4) -> 1504 waves (~6/CU) and no
// __syncthreads in the loop (wave-private LDS staging, lgkmcnt-ordered).
// Bit condition (iou>0.7 && j>i && j<NIN_) is decision-identical to R3/R4's
// kbeg/kend loop; IoU expression (incl. IEEE div) unchanged.
__global__ __launch_bounds__(256) void k5_mat(const float* __restrict__ rois_s,
                                              unsigned long long* __restrict__ mat) {
    const int b = blockIdx.y, rb = blockIdx.x;
    const int t = threadIdx.x, wave = t >> 6, lane = t & 63;
    const int i = rb * 64 + lane;
    const bool rowok = (i < NIN_);
    __shared__ float cs[4][5][64];   // [wave][y1,x1,y2,x2,area][col]
    const float* bb = rois_s + (size_t)b * NIN_ * 4;

    float r0 = 0, r1 = 0, r2 = 0, r3 = 0, ra = 0;
    if (rowok) {
        float4 v = *(const float4*)&bb[(size_t)i * 4];
        r0 = v.x; r1 = v.y; r2 = v.z; r3 = v.w;
        ra = (v.z - v.x) * (v.w - v.y);
    }
    unsigned long long* mrow = mat + ((size_t)b * NIN_ + (size_t)(rowok ? i : 0)) * NW;

    // lower-triangle words (all j <= i): zero, matches R3/R4 semantics
    if (rowok)
        for (int cb = wave; cb < rb; cb += 4) mrow[cb] = 0ull;

    for (int cb = rb + wave; cb < NW; cb += 4) {
        const int j0 = cb * 64;
        const int j  = j0 + lane;
        float4 v;
        if (j < NIN_) v = *(const float4*)&bb[(size_t)j * 4];
        else { v.x = 0; v.y = 0; v.z = 0; v.w = 0; }
        cs[wave][0][lane] = v.x; cs[wave][1][lane] = v.y;
        cs[wave][2][lane] = v.z; cs[wave][3][lane] = v.w;
        cs[wave][4][lane] = (v.z - v.x) * (v.w - v.y);
        // wave-internal LDS visibility: compiler-inserted lgkmcnt, no barrier
        unsigned long long wm = 0;
        if (rowok) {
#pragma unroll 8
            for (int k = 0; k < 64; ++k) {
                float yy1 = fmaxf(r0, cs[wave][0][k]), xx1 = fmaxf(r1, cs[wave][1][k]);
                float yy2 = fminf(r2, cs[wave][2][k]), xx2 = fminf(r3, cs[wave][3][k]);
                float inter = fmaxf(yy2 - yy1, 0.f) * fmaxf(xx2 - xx1, 0.f);
                float iou = inter / (ra + cs[wave][4][k] - inter + 1e-9f);
                int jj = j0 + k;
                if ((iou > 0.7f) && (jj > i) && (jj < NIN_)) wm |= (1ull << k);
            }
            mrow[cb] = wm;
        }
    }
}

// ---------------- K5b: serial greedy scan over bitmask ----------------
__global__ __launch_bounds__(64) void k5_scan(const unsigned long long* __restrict__ mat,
                                              const float* __restrict__ rois_s,
                                              const int* __restrict__ valid_s,
                                              float* __restrict__ out) {
    const int b = blockIdx.x, t = threadIdx.x;
    for (int k = t; k < NOUT2 * 4; k += 64) out[O_ROI + (size_t)b * NOUT2 * 4 + k] = 0.f;
    for (int k = t; k < NOUT2; k += 64) out[O_IDX + (size_t)b * NOUT2 + k] = (float)b;

    unsigned long long A = 0, B = 0;
    for (int w = 0; w < NW; ++w) {
        int i = w * 64 + t;
        int v = (i < NIN_) ? valid_s[b * NIN_ + i] : 0;
        unsigned long long m = __ballot(v == 0);
        if (w < 64) { if (t == w) A = m; }
        else        { if (t == w - 64) B = m; }
    }

    const unsigned long long* mb = mat + (size_t)b * NIN_ * NW;
    const float* bb = rois_s + (size_t)b * NIN_ * 4;
    int kept = 0;
    for (int w = 0; w < NW && kept < NOUT2; ++w) {
        unsigned long long cur = (w < 64) ? __shfl(A, w) : __shfl(B, w - 64);
        unsigned long long avail = ~cur;
        while (avail != 0ull && kept < NOUT2) {
            int bit = __builtin_ctzll(avail);
            int i = w * 64 + bit;
            if (t == 0) {
                float4 bx = *(const float4*)&bb[(size_t)i * 4];
                *(float4*)&out[O_ROI + ((size_t)b * NOUT2 + kept) * 4] = bx;
            }
            kept++;
            if (kept >= NOUT2) break;
            const unsigned long long* row = mb + (size_t)i * NW;
            unsigned long long rA = row[t];
            unsigned long long rB = (t < NW - 64) ? row[64 + t] : 0ull;
            A |= rA; B |= rB;
            unsigned long long rw = (w < 64) ? __shfl(rA, w) : __shfl(rB, w - 64);
            avail &= ~rw;
            avail &= ~(1ull << bit);
        }
    }
}

// ---------------- launch ----------------
extern "C" void kernel_launch(void* const* d_in, const int* in_sizes, int n_in,
                              void* d_out, int out_size, void* d_ws, size_t ws_size,
                              hipStream_t stream) {
    const float* x       = (const float*)d_in[0];
    const float* conv_w  = (const float*)d_in[1];
    const float* conv_b  = (const float*)d_in[2];
    const float* score_w = (const float*)d_in[3];
    const float* score_b = (const float*)d_in[4];
    const float* loc_w   = (const float*)d_in[5];
    const float* loc_b   = (const float*)d_in[6];
    float* out = (float*)d_out;
    float* ws  = (float*)d_ws;    // high-water 43.0 MB (same as R1-R4)

    f16* whi = (f16*)(ws + W_WHI);
    f16* wlo = (f16*)(ws + W_WLO);

    k0w<<<2359296 / 256, 256, 0, stream>>>(conv_w, whi, wlo);
    k1_mfma<<<dim3(32, 4, 4), 256, 0, stream>>>(x, whi, wlo, conv_b, ws + W_H);
    k2_conv1<<<dim3(64, 4), 256, 0, stream>>>(ws + W_H, score_w, score_b, loc_w, loc_b, out);
    // zero hist + cnt + cut (region aliases h, so zero AFTER K2 is done with h)
    hipMemsetAsync(ws + W_HIST, 0, (size_t)16448 * 4, stream);
    k3_prop<<<dim3(144, 4), 256, 0, stream>>>(out, ws + W_R4, ws + W_SK, (int*)(ws + W_HIST));
    k4b_scan<<<1, 256, 0, stream>>>((const int*)(ws + W_HIST), (int*)(ws + W_CUT));
    k4c_compact<<<dim3(144, 4), 256, 0, stream>>>(ws + W_SK, (const int*)(ws + W_CUT),
                                                  (int*)(ws + W_CNT), (int*)(ws + W_CIDX),
                                                  (unsigned long long*)(ws + W_CKEY));
    k4d_rank<<<dim3(144, 4), 256, 0, stream>>>((const int*)(ws + W_CNT), (const int*)(ws + W_CIDX),
                                               (const unsigned long long*)(ws + W_CKEY),
                                               ws + W_R4, ws + W_RS, (int*)(ws + W_VS));
    k5_mat<<<dim3(NW, BATCH), 256, 0, stream>>>(ws + W_RS, (unsigned long long*)(ws + W_MAT));
    k5_scan<<<BATCH, 64, 0, stream>>>((const unsigned long long*)(ws + W_MAT),
                                      ws + W_RS, (const int*)(ws + W_VS), out);
}

// Round 7
// 1025.226 us; speedup vs baseline: 3.7734x; 1.2112x over previous
//
#include <hip/hip_runtime.h>
#include <cstdint>
#include <cmath>

// ---------------- constants ----------------
namespace {
constexpr int BATCH = 4;
constexpr int CIN   = 512;
constexpr int CMID  = 512;
constexpr int HSZ   = 64, WSZ = 64, HWP = 4096;
constexpr int NA    = 36864;          // HW * 9 anchors
constexpr int NIN_  = 6000;
constexpr int NOUT2 = 300;
constexpr int NW    = 94;             // ceil(6000/64) u64 words per bitmask row

// d_out layout (float offsets)
constexpr size_t O_SC  = 0;           // rpn_scores (4,36864,2)
constexpr size_t O_LC  = 294912;      // rpn_locs   (4,36864,4)
constexpr size_t O_ROI = 884736;      // rois       (1200,4)
constexpr size_t O_IDX = 889536;      // roi_indices(1200)
constexpr size_t O_ANC = 890736;      // anchors    (36864,4)

// d_ws layout (float offsets). Phase A: h + w-split. Phase B (post-K2) aliases h.
// High-water = 10747904 floats = 43.0 MB (same as the proven R1-R5 layout).
constexpr size_t W_H    = 0;          // 8388608 floats (conv hidden, NCHW)
constexpr size_t W_WHI  = 8388608;    // 2359296 f16 (= 1179648 floats) W hi, [kk][co][ci]
constexpr size_t W_WLO  = 9568256;    // 2359296 f16 W lo (scaled 2048)
constexpr size_t W_R4   = 0;          // 589824  rois per anchor (aliases h: used after K2 only)
constexpr size_t W_SK   = 589824;     // 147456  score keys (fg or -inf)
constexpr size_t W_HIST = 737280;     // 16384 ints (4 x 4096 bins), level-1 hist
constexpr size_t W_CNT  = 753664;     // 4 ints   compact counter
constexpr size_t W_CUT  = 753668;     // 4 ints   cut1
constexpr size_t W_NHI1 = 753672;     // 4 ints   cumulative count above cut1 bin
constexpr size_t W_CUT2 = 753676;     // 4 ints
constexpr size_t W_NHI2 = 753680;     // 4 ints
constexpr size_t W_CUT3 = 753684;     // 4 ints
constexpr size_t W_ZERO = 753688;     // 4 ints   (stays zero; cum_in for level 1)
constexpr size_t W_NHI3 = 753692;     // 4 ints   (dummy cum_out for level 3)
constexpr size_t W_H2   = 753728;     // 16384 ints, level-2 hist
constexpr size_t W_H3   = 770112;     // 16384 ints, level-3 hist (ends 786496)
constexpr size_t W_CKEY = 901184;     // 294912 floats = 147456 u64 keys (8B aligned)
constexpr size_t W_RS   = 1196096;    // 96000  sorted rois (4,6000,4)
constexpr size_t W_VS   = 1292096;    // 24000 ints sorted validity
constexpr size_t W_MAT  = 1316096;    // 4*6000*94 u64 = 4512000 floats (suppression bits)
} // namespace

typedef _Float16 f16;
typedef __attribute__((ext_vector_type(4))) _Float16 f16x4;
typedef __attribute__((ext_vector_type(8))) _Float16 f16x8;
typedef __attribute__((ext_vector_type(4))) float f32x4;

// ---------------- K0w: split conv_w*64 into f16 hi/lo, layout [kk][co][ci] ----------------
__global__ __launch_bounds__(256) void k0w(const float* __restrict__ w,
                                           f16* __restrict__ whi, f16* __restrict__ wlo) {
    int o = blockIdx.x * 256 + threadIdx.x;     // 2359296 total
    int ci = o & 511;
    int r  = o >> 9;
    int co = r & 511;
    int kk = r >> 9;
    float f = w[(co * CIN + ci) * 9 + kk] * 64.0f;   // scale 64: keep hi out of f16-subnormals
    f16 hv = (f16)f;
    whi[o] = hv;
    wlo[o] = (f16)((f - (float)hv) * 2048.0f);       // lo scaled 2^11 into normal range
}

// ---------------- K1: 3x3 conv + bias + ReLU via f16-split MFMA (3 products) ----------
// 9-shift implicit GEMM. Block = 2 image rows x 128 co; wave = 1 row(64px) x 64 co.
// grid (32 row-pairs, 4 co-groups, 4 batch) = 512 blocks -> 2 blocks/CU. LDS 58.6 KB.
__global__ __launch_bounds__(256, 2) void k1_mfma(const float* __restrict__ x,
                                                  const f16* __restrict__ gwh,
                                                  const f16* __restrict__ gwl,
                                                  const float* __restrict__ bias,
                                                  float* __restrict__ h) {
    const int pt = blockIdx.x, cg = blockIdx.y, b = blockIdx.z;
    const int y0 = pt * 2, co0 = cg * 128;
    const int t = threadIdx.x;
    const int wave = t >> 6, lane = t & 63;
    const int wrow = wave >> 1, wco = wave & 1;
    const int m = lane & 15, q = lane >> 4;

    // X tile: [hi/lo][(row*66 + col)*40 + ci]  (rows y0-1..y0+2, cols = img_x+1, ci 0..31, pad to 40)
    __shared__ __align__(16) f16 xs[2][4 * 66 * 40];
    // W tile: [slot][hi/lo][co*32 + ci]
    __shared__ __align__(16) f16 wt[2][2][128 * 32];

    f32x4 acc1[4][4], acc2[4][4];
#pragma unroll
    for (int i = 0; i < 4; ++i)
#pragma unroll
        for (int j = 0; j < 4; ++j) { acc1[i][j] = (f32x4)0.0f; acc2[i][j] = (f32x4)0.0f; }

    // X staging roles
    const int cq = t & 7, srow = (t >> 3) & 3, cseg = t >> 5;
    const int gy = y0 - 1 + srow;
    const bool yok = (gy >= 0 && gy < HSZ);

    // zero the padding columns (img_x = -1 -> col 0, img_x = 64 -> col 65); never rewritten
    if (t < 128) {
        int buf = t >> 6, rr = (t >> 4) & 3, cc = ((t >> 3) & 1) ? 65 : 0, cq2 = t & 7;
        f16x4 z = (f16x4)(f16)0.0f;
        *(f16x4*)&xs[buf][(rr * 66 + cc) * 40 + cq2 * 4] = z;
    }

    // stage W for ks=0 into slot 0
    {
#pragma unroll
        for (int s = 0; s < 2; ++s) {
            int idx = s * 256 + t;               // 512 tasks of 8 f16
            int co_l = idx >> 2, q8 = idx & 3;
            size_t g = ((size_t)(co0 + co_l)) * 512 + q8 * 8;   // kk=0, chunk=0
            *(f16x8*)&wt[0][0][co_l * 32 + q8 * 8] = *(const f16x8*)&gwh[g];
            *(f16x8*)&wt[0][1][co_l * 32 + q8 * 8] = *(const f16x8*)&gwl[g];
        }
    }

    int chunk = 0, kk = 0;
    for (int ks = 0; ks < 144; ++ks) {
        const int slot = ks & 1;
        __syncthreads();   // all waves done with ks-1 compute -> safe to overwrite slot^1 and (if kk==0) X

        if (kk == 0) {
            // stage X(chunk): thread = (cq, srow, cseg); 4 ci x 8 cols
            float vb[4][8];
            const float* xp = x + ((size_t)(b * CIN + chunk * 32 + cq * 4)) * HWP + gy * WSZ + cseg * 8;
#pragma unroll
            for (int i = 0; i < 4; ++i) {
                if (yok) {
                    float4 u0 = *(const float4*)(xp + (size_t)i * HWP);
                    float4 u1 = *(const float4*)(xp + (size_t)i * HWP + 4);
                    vb[i][0] = u0.x; vb[i][1] = u0.y; vb[i][2] = u0.z; vb[i][3] = u0.w;
                    vb[i][4] = u1.x; vb[i][5] = u1.y; vb[i][6] = u1.z; vb[i][7] = u1.w;
                } else {
#pragma unroll
                    for (int jj = 0; jj < 8; ++jj) vb[i][jj] = 0.0f;
                }
            }
#pragma unroll
            for (int j = 0; j < 8; ++j) {
                int c = (j + cq) & 7;            // k-rotation: spread LDS banks across lanes
                int col = cseg * 8 + c + 1;
                f16x4 hv, lv;
#pragma unroll
                for (int i = 0; i < 4; ++i) {
                    float f = vb[i][c];
                    f16 hf = (f16)f;
                    hv[i] = hf;
                    lv[i] = (f16)((f - (float)hf) * 2048.0f);
                }
                int base = (srow * 66 + col) * 40 + cq * 4;
                *(f16x4*)&xs[0][base] = hv;
                *(f16x4*)&xs[1][base] = lv;
            }
        }

        // prefetch-stage W(ks+1) into slot^1 (overlaps compute; consumed next iter)
        if (ks + 1 < 144) {
            int kk2 = kk + 1, ch2 = chunk;
            if (kk2 == 9) { kk2 = 0; ch2++; }
#pragma unroll
            for (int s = 0; s < 2; ++s) {
                int idx = s * 256 + t;
                int co_l = idx >> 2, q8 = idx & 3;
                size_t g = ((size_t)(kk2 * 512 + co0 + co_l)) * 512 + ch2 * 32 + q8 * 8;
                *(f16x8*)&wt[slot ^ 1][0][co_l * 32 + q8 * 8] = *(const f16x8*)&gwh[g];
                *(f16x8*)&wt[slot ^ 1][1][co_l * 32 + q8 * 8] = *(const f16x8*)&gwl[g];
            }
        }

        if (kk == 0) __syncthreads();   // X(chunk) (and prologue W0) ready

        // compute shift kk with W[slot]
        const int ky = (kk >= 6) ? 2 : (kk >= 3) ? 1 : 0;
        const int kx = kk - ky * 3;
        const int rs = wrow + ky;

        f16x8 bh[4], bl[4], ah[4], al[4];
#pragma unroll
        for (int nt = 0; nt < 4; ++nt) {
            int off = (wco * 64 + nt * 16 + m) * 32 + q * 8;
            bh[nt] = *(const f16x8*)&wt[slot][0][off];
            bl[nt] = *(const f16x8*)&wt[slot][1][off];
        }
#pragma unroll
        for (int ct = 0; ct < 4; ++ct) {
            int off = (rs * 66 + ct * 16 + m + kx) * 40 + q * 8;
            ah[ct] = *(const f16x8*)&xs[0][off];
            al[ct] = *(const f16x8*)&xs[1][off];
        }
#pragma unroll
        for (int ct = 0; ct < 4; ++ct)
#pragma unroll
            for (int nt = 0; nt < 4; ++nt) {
                acc1[ct][nt] = __builtin_amdgcn_mfma_f32_16x16x32_f16(ah[ct], bh[nt], acc1[ct][nt], 0, 0, 0);
                acc2[ct][nt] = __builtin_amdgcn_mfma_f32_16x16x32_f16(ah[ct], bl[nt], acc2[ct][nt], 0, 0, 0);
                acc2[ct][nt] = __builtin_amdgcn_mfma_f32_16x16x32_f16(al[ct], bh[nt], acc2[ct][nt], 0, 0, 0);
            }

        ++kk;
        if (kk == 9) { kk = 0; ++chunk; }
    }

    // epilogue: h = (acc1 + acc2*2^-11)*2^-6 + bias, relu
    const int y = y0 + wrow;
#pragma unroll
    for (int nt = 0; nt < 4; ++nt) {
        const int co = co0 + wco * 64 + nt * 16 + m;    // D: n = lane&15
        const float bv = bias[co];
        size_t rowbase = ((size_t)(b * CMID + co)) * HWP + y * WSZ;
#pragma unroll
        for (int ct = 0; ct < 4; ++ct) {
            float4 o;
            o.x = fmaxf((acc1[ct][nt][0] + acc2[ct][nt][0] * (1.0f / 2048.0f)) * (1.0f / 64.0f) + bv, 0.0f);
            o.y = fmaxf((acc1[ct][nt][1] + acc2[ct][nt][1] * (1.0f / 2048.0f)) * (1.0f / 64.0f) + bv, 0.0f);
            o.z = fmaxf((acc1[ct][nt][2] + acc2[ct][nt][2] * (1.0f / 2048.0f)) * (1.0f / 64.0f) + bv, 0.0f);
            o.w = fmaxf((acc1[ct][nt][3] + acc2[ct][nt][3] * (1.0f / 2048.0f)) * (1.0f / 64.0f) + bv, 0.0f);
            *(float4*)&h[rowbase + ct * 16 + q * 4] = o;   // D: m = q*4+reg -> img x
        }
    }
}

// ---------------- K2: 1x1 convs (score 18 + loc 36) -> d_out in NHWC-anchor layout ----------
// grid (64 rows, 4 batch); block 256; thread = 4 channels x 4 px
__global__ __launch_bounds__(256) void k2_conv1(const float* __restrict__ h,
                                                const float* __restrict__ sw,
                                                const float* __restrict__ sb,
                                                const float* __restrict__ lw,
                                                const float* __restrict__ lb,
                                                float* __restrict__ out) {
    const int y = blockIdx.x;
    const int b = blockIdx.y;
    const int t = threadIdx.x;
    const int c4  = (t & 15) * 4;
    const int px4 = (t >> 4) * 4;
    __shared__ __align__(16) float hs[1024];        // [ci(16)][px(64)]
    __shared__ __align__(16) float wsm[16 * 68];    // [ci][c] padded

    float acc[4][4];
#pragma unroll
    for (int i = 0; i < 4; ++i)
#pragma unroll
        for (int j = 0; j < 4; ++j) acc[i][j] = 0.f;

    const int s_px = (t & 15) * 4;
    const int s_ci = t >> 4;
    for (int ci0 = 0; ci0 < CMID; ci0 += 16) {
        *(float4*)&hs[s_ci * 64 + s_px] =
            *(const float4*)&h[((size_t)(b * CMID + ci0 + s_ci)) * HWP + y * 64 + s_px];
#pragma unroll
        for (int k = 0; k < 4; ++k) {
            int idx = k * 256 + t;
            int ci = idx & 15, c = idx >> 4;
            float v = 0.f;
            if (c < 18) v = sw[c * 512 + ci0 + ci];
            else if (c < 54) v = lw[(c - 18) * 512 + ci0 + ci];
            wsm[ci * 68 + c] = v;
        }
        __syncthreads();
#pragma unroll
        for (int ci = 0; ci < 16; ++ci) {
            float4 hv = *(const float4*)&hs[ci * 64 + px4];
            float4 wv = *(const float4*)&wsm[ci * 68 + c4];
            acc[0][0] = fmaf(wv.x, hv.x, acc[0][0]);
            acc[0][1] = fmaf(wv.x, hv.y, acc[0][1]);
            acc[0][2] = fmaf(wv.x, hv.z, acc[0][2]);
            acc[0][3] = fmaf(wv.x, hv.w, acc[0][3]);
            acc[1][0] = fmaf(wv.y, hv.x, acc[1][0]);
            acc[1][1] = fmaf(wv.y, hv.y, acc[1][1]);
            acc[1][2] = fmaf(wv.y, hv.z, acc[1][2]);
            acc[1][3] = fmaf(wv.y, hv.w, acc[1][3]);
            acc[2][0] = fmaf(wv.z, hv.x, acc[2][0]);
            acc[2][1] = fmaf(wv.z, hv.y, acc[2][1]);
            acc[2][2] = fmaf(wv.z, hv.z, acc[2][2]);
            acc[2][3] = fmaf(wv.z, hv.w, acc[2][3]);
            acc[3][0] = fmaf(wv.w, hv.x, acc[3][0]);
            acc[3][1] = fmaf(wv.w, hv.y, acc[3][1]);
            acc[3][2] = fmaf(wv.w, hv.z, acc[3][2]);
            acc[3][3] = fmaf(wv.w, hv.w, acc[3][3]);
        }
        __syncthreads();
    }

#pragma unroll
    for (int cc = 0; cc < 4; ++cc) {
        int c = c4 + cc;
        if (c >= 54) break;
        float bv = (c < 18) ? sb[c] : lb[c - 18];
#pragma unroll
        for (int pp = 0; pp < 4; ++pp) {
            int px = y * 64 + px4 + pp;
            float v = acc[cc][pp] + bv;
            if (c < 18)
                out[O_SC + (size_t)b * 73728 + (size_t)px * 18 + c] = v;
            else
                out[O_LC + (size_t)b * 147456 + (size_t)px * 36 + (c - 18)] = v;
        }
    }
}

// ---------------- K3: anchors + softmax-fg + loc2bbox + clip + level-1 histogram -------
// grid (144, 4); block 256 -> one thread per anchor
__global__ __launch_bounds__(256) void k3_prop(float* __restrict__ out,
                                               float* __restrict__ rois4,
                                               float* __restrict__ skey,
                                               int* __restrict__ hist) {
    __shared__ int lh[4096];
    const int t = threadIdx.x;
    for (int k = t; k < 4096; k += 256) lh[k] = 0;
    __syncthreads();

    const int p = blockIdx.x * 256 + t;
    const int b = blockIdx.y;
    const int px = p / 9;
    const int a  = p - px * 9;
    const int yy = px >> 6, xx = px & 63;
    const int ri = a / 3, si = a - ri * 3;
    const double rat[3] = {0.5, 1.0, 2.0};
    const double scl[3] = {8.0, 16.0, 32.0};
    double hhd = 16.0 * scl[si] * sqrt(rat[ri]);
    double wwd = 16.0 * scl[si] * sqrt(1.0 / rat[ri]);
    float a0 = (float)(8.0 - hhd / 2.0), a1 = (float)(8.0 - wwd / 2.0);
    float a2 = (float)(8.0 + hhd / 2.0), a3 = (float)(8.0 + wwd / 2.0);
    float sy = (float)(yy * 16), sx = (float)(xx * 16);
    float A0 = sy + a0, A1 = sx + a1, A2 = sy + a2, A3 = sx + a3;
    if (b == 0) {
        float4 av; av.x = A0; av.y = A1; av.z = A2; av.w = A3;
        *(float4*)&out[O_ANC + (size_t)p * 4] = av;
    }
    const float* sc = out + O_SC + (size_t)b * 73728 + (size_t)px * 18 + a * 2;
    float s0 = sc[0], s1 = sc[1];
    float m = fmaxf(s0, s1);
    float e0 = expf(s0 - m), e1 = expf(s1 - m);
    float fg = e1 / (e0 + e1);
    const float* lc = out + O_LC + (size_t)b * 147456 + (size_t)px * 36 + a * 4;
    float dy = lc[0], dxv = lc[1], dh = lc[2], dwv = lc[3];
    float ah = A2 - A0, aw = A3 - A1;
    float cy = A0 + 0.5f * ah, cx = A1 + 0.5f * aw;
    float cty = dy * ah + cy, ctx = dxv * aw + cx;
    float th = expf(dh) * ah, tw = expf(dwv) * aw;
    float ry1 = cty - 0.5f * th, rx1 = ctx - 0.5f * tw;
    float ry2 = cty + 0.5f * th, rx2 = ctx + 0.5f * tw;
    float y1 = fminf(fmaxf(ry1, 0.f), 1024.f);
    float y2 = fminf(fmaxf(ry2, 0.f), 1024.f);
    float x1 = fminf(fmaxf(rx1, 0.f), 1024.f);
    float x2 = fminf(fmaxf(rx2, 0.f), 1024.f);
    bool valid = ((y2 - y1) >= 16.f) && ((x2 - x1) >= 16.f);
    float sk = valid ? fg : -__builtin_inff();
    float4 rv; rv.x = y1; rv.y = x1; rv.z = y2; rv.w = x2;
    *(float4*)&rois4[((size_t)b * NA + p) * 4] = rv;
    skey[(size_t)b * NA + p] = sk;
    unsigned u = __float_as_uint(sk);
    u = (u & 0x80000000u) ? ~u : (u | 0x80000000u);
    atomicAdd(&lh[u >> 20], 1);
    __syncthreads();
    for (int k = t; k < 4096; k += 256) {
        int v = lh[k];
        if (v) atomicAdd(&hist[b * 4096 + k], v);
    }
}

// ---------------- K4s: generic suffix-scan of a 4096-bin histogram -------------------
// Finds cut s.t. cum_in + suffix(cut) >= 6000 > cum_in + suffix(cut+1); writes
// cum_out = cum_in + suffix(cut+1) (count strictly above the cut bin).
__global__ __launch_bounds__(256) void k4scan(const int* __restrict__ hist,
                                              const int* __restrict__ cum_in,
                                              int* __restrict__ cut,
                                              int* __restrict__ cum_out) {
    __shared__ int hl[4096];
    __shared__ int tsum[256];
    const int t = threadIdx.x;
    for (int b = 0; b < BATCH; ++b) {
        const int target = NIN_ - cum_in[b];   // >= 1 by construction
        for (int k = t; k < 4096; k += 256) hl[k] = hist[b * 4096 + k];
        __syncthreads();
        int s = 0;
#pragma unroll
        for (int j = 0; j < 16; ++j) s += hl[t * 16 + j];
        tsum[t] = s;
        __syncthreads();
        if (t == 0) {
            int run = 0;
            for (int tt = 255; tt >= 0; --tt) { int tmp = tsum[tt]; tsum[tt] = run; run += tmp; }
        }
        __syncthreads();
        int run = tsum[t];
        for (int v = t * 16 + 15; v >= t * 16; --v) {
            int prev = run;
            run += hl[v];
            if (run >= target && prev < target) {
                cut[b] = v;
                cum_out[b] = cum_in[b] + prev;
            }
        }
        __syncthreads();
    }
}

// ---------------- K4h: refinement histograms (level 2: score bits 8..19; level 3: idx>>4) --
__global__ __launch_bounds__(256) void k4h(const float* __restrict__ skey,
                                           const int* __restrict__ cut1,
                                           const int* __restrict__ cut2,
                                           int* __restrict__ hist, int level) {
    __shared__ int lh[4096];
    const int t = threadIdx.x;
    for (int k = t; k < 4096; k += 256) lh[k] = 0;
    __syncthreads();
    const int p = blockIdx.x * 256 + t;
    const int b = blockIdx.y;
    float sk = skey[(size_t)b * NA + p];
    unsigned u = __float_as_uint(sk);
    u = (u & 0x80000000u) ? ~u : (u | 0x80000000u);
    int b1 = (int)(u >> 20), b2 = (int)((u >> 8) & 0xFFFu);
    if (level == 2) {
        if (b1 == cut1[b]) atomicAdd(&lh[b2], 1);
    } else {
        if (b1 == cut1[b] && b2 == cut2[b]) atomicAdd(&lh[(36863 - p) >> 4], 1);
    }
    __syncthreads();
    for (int k = t; k < 4096; k += 256) {
        int v = lh[k];
        if (v) atomicAdd(&hist[b * 4096 + k], v);
    }
}

// ---------------- K4c: compact candidate keys per 3-level cut --------------------------
// take = key-digits lexicographically >= (cut1,cut2,cut3). Level-3 bins hold <=16
// elements (idx unique) -> 6000 <= C < 6016 for ANY input distribution.
__global__ __launch_bounds__(256) void k4c_compact(const float* __restrict__ skey,
                                                   const int* __restrict__ cut1,
                                                   const int* __restrict__ cut2,
                                                   const int* __restrict__ cut3,
                                                   int* __restrict__ cnt,
                                                   unsigned long long* __restrict__ ckey) {
    const int p = blockIdx.x * 256 + threadIdx.x;
    const int b = blockIdx.y;
    float sk = skey[(size_t)b * NA + p];
    unsigned u = __float_as_uint(sk);
    u = (u & 0x80000000u) ? ~u : (u | 0x80000000u);
    int b1 = (int)(u >> 20), b2 = (int)((u >> 8) & 0xFFFu), b3 = (36863 - p) >> 4;
    int c1 = cut1[b], c2 = cut2[b], c3 = cut3[b];
    bool take = (b1 > c1) || (b1 == c1 && (b2 > c2 || (b2 == c2 && b3 >= c3)));
    if (take) {
        int pos = atomicAdd(&cnt[b], 1);
        // 48-bit key: score bits (monotone) then inverted index -> unique, matches
        // stable argsort(-s) tie-breaking. p recoverable: p = 36863 - (key & 0xFFFF).
        ckey[(size_t)b * NA + pos] =
            ((unsigned long long)u << 16) | (unsigned long long)(36863 - p);
    }
}

// ---------------- K4d: in-LDS bitonic sort of candidate keys, emit top-6000 ----------
// One 1024-thread block per batch. 8192-element descending bitonic network
// (91 phases, disjoint pairs per phase -> one barrier per phase). C < 6016 (proven
// by 3-level radix cut) << 8192. Keys unique -> ranks identical to counting version.
__global__ __launch_bounds__(1024) void k4d_sort(const int* __restrict__ cnt,
                                                 const unsigned long long* __restrict__ ckey,
                                                 const float* __restrict__ rois4,
                                                 float* __restrict__ rois_s,
                                                 int* __restrict__ valid_s) {
    const int b = blockIdx.x, t = threadIdx.x;
    const int C = min(cnt[b], 8192);
    __shared__ unsigned long long keys[8192];
#pragma unroll
    for (int s = 0; s < 8; ++s) {
        int i = s * 1024 + t;
        keys[i] = (i < C) ? ckey[(size_t)b * NA + i] : 0ull;
    }
    __syncthreads();
    for (int k = 2; k <= 8192; k <<= 1) {
        for (int j = k >> 1; j > 0; j >>= 1) {
#pragma unroll
            for (int s = 0; s < 8; ++s) {
                int i = s * 1024 + t;
                int ixj = i ^ j;
                if (ixj > i) {
                    unsigned long long x = keys[i], y = keys[ixj];
                    bool up = ((i & k) == 0);            // descending overall
                    if (up ? (x < y) : (x > y)) { keys[i] = y; keys[ixj] = x; }
                }
            }
            __syncthreads();
        }
    }
    // ranks 0..5999: recover anchor index from key, gather box, emit validity
    for (int r = t; r < NIN_; r += 1024) {
        unsigned long long key = keys[r];
        int p = 36863 - (int)(key & 0xFFFFull);
        const float4 bx = *(const float4*)&rois4[((size_t)b * NA + p) * 4];
        *(float4*)&rois_s[((size_t)b * NIN_ + r) * 4] = bx;
        valid_s[b * NIN_ + r] = ((unsigned)(key >> 16) != 0x007FFFFFu) ? 1 : 0;
    }
}

// ---------------- K5a: pairwise suppression bitmask matrix ----------------
// grid (94 rowblocks, 4 batch); block 256 = 4 waves, all on the same 64 rows.
// Waves split column-blocks (cb = rb+wave, step 4) -> 1504 waves (~6/CU) and no
// __syncthreads in the loop (wave-private LDS staging, lgkmcnt-ordered).
__global__ __launch_bounds__(256) void k5_mat(const float* __restrict__ rois_s,
                                              unsigned long long* __restrict__ mat) {
    const int b = blockIdx.y, rb = blockIdx.x;
    const int t = threadIdx.x, wave = t >> 6, lane = t & 63;
    const int i = rb * 64 + lane;
    const bool rowok = (i < NIN_);
    __shared__ float cs[4][5][64];   // [wave][y1,x1,y2,x2,area][col]
    const float* bb = rois_s + (size_t)b * NIN_ * 4;

    float r0 = 0, r1 = 0, r2 = 0, r3 = 0, ra = 0;
    if (rowok) {
        float4 v = *(const float4*)&bb[(size_t)i * 4];
        r0 = v.x; r1 = v.y; r2 = v.z; r3 = v.w;
        ra = (v.z - v.x) * (v.w - v.y);
    }
    unsigned long long* mrow = mat + ((size_t)b * NIN_ + (size_t)(rowok ? i : 0)) * NW;

    // lower-triangle words (all j <= i): zero
    if (rowok)
        for (int cb = wave; cb < rb; cb += 4) mrow[cb] = 0ull;

    for (int cb = rb + wave; cb < NW; cb += 4) {
        const int j0 = cb * 64;
        const int j  = j0 + lane;
        float4 v;
        if (j < NIN_) v = *(const float4*)&bb[(size_t)j * 4];
        else { v.x = 0; v.y = 0; v.z = 0; v.w = 0; }
        cs[wave][0][lane] = v.x; cs[wave][1][lane] = v.y;
        cs[wave][2][lane] = v.z; cs[wave][3][lane] = v.w;
        cs[wave][4][lane] = (v.z - v.x) * (v.w - v.y);
        unsigned long long wm = 0;
        if (rowok) {
#pragma unroll 8
            for (int k = 0; k < 64; ++k) {
                float yy1 = fmaxf(r0, cs[wave][0][k]), xx1 = fmaxf(r1, cs[wave][1][k]);
                float yy2 = fminf(r2, cs[wave][2][k]), xx2 = fminf(r3, cs[wave][3][k]);
                float inter = fmaxf(yy2 - yy1, 0.f) * fmaxf(xx2 - xx1, 0.f);
                float iou = inter / (ra + cs[wave][4][k] - inter + 1e-9f);
                int jj = j0 + k;
                if ((iou > 0.7f) && (jj > i) && (jj < NIN_)) wm |= (1ull << k);
            }
            mrow[cb] = wm;
        }
    }
}

// ---------------- K5b: serial greedy scan over bitmask ----------------
__global__ __launch_bounds__(64) void k5_scan(const unsigned long long* __restrict__ mat,
                                              const float* __restrict__ rois_s,
                                              const int* __restrict__ valid_s,
                                              float* __restrict__ out) {
    const int b = blockIdx.x, t = threadIdx.x;
    for (int k = t; k < NOUT2 * 4; k += 64) out[O_ROI + (size_t)b * NOUT2 * 4 + k] = 0.f;
    for (int k = t; k < NOUT2; k += 64) out[O_IDX + (size_t)b * NOUT2 + k] = (float)b;

    unsigned long long A = 0, B = 0;
    for (int w = 0; w < NW; ++w) {
        int i = w * 64 + t;
        int v = (i < NIN_) ? valid_s[b * NIN_ + i] : 0;
        unsigned long long m = __ballot(v == 0);
        if (w < 64) { if (t == w) A = m; }
        else        { if (t == w - 64) B = m; }
    }

    const unsigned long long* mb = mat + (size_t)b * NIN_ * NW;
    const float* bb = rois_s + (size_t)b * NIN_ * 4;
    int kept = 0;
    for (int w = 0; w < NW && kept < NOUT2; ++w) {
        unsigned long long cur = (w < 64) ? __shfl(A, w) : __shfl(B, w - 64);
        unsigned long long avail = ~cur;
        while (avail != 0ull && kept < NOUT2) {
            int bit = __builtin_ctzll(avail);
            int i = w * 64 + bit;
            if (t == 0) {
                float4 bx = *(const float4*)&bb[(size_t)i * 4];
                *(float4*)&out[O_ROI + ((size_t)b * NOUT2 + kept) * 4] = bx;
            }
            kept++;
            if (kept >= NOUT2) break;
            const unsigned long long* row = mb + (size_t)i * NW;
            unsigned long long rA = row[t];
            unsigned long long rB = (t < NW - 64) ? row[64 + t] : 0ull;
            A |= rA; B |= rB;
            unsigned long long rw = (w < 64) ? __shfl(rA, w) : __shfl(rB, w - 64);
            avail &= ~rw;
            avail &= ~(1ull << bit);
        }
    }
}

// ---------------- launch ----------------
extern "C" void kernel_launch(void* const* d_in, const int* in_sizes, int n_in,
                              void* d_out, int out_size, void* d_ws, size_t ws_size,
                              hipStream_t stream) {
    const float* x       = (const float*)d_in[0];
    const float* conv_w  = (const float*)d_in[1];
    const float* conv_b  = (const float*)d_in[2];
    const float* score_w = (const float*)d_in[3];
    const float* score_b = (const float*)d_in[4];
    const float* loc_w   = (const float*)d_in[5];
    const float* loc_b   = (const float*)d_in[6];
    float* out = (float*)d_out;
    float* ws  = (float*)d_ws;    // high-water 43.0 MB (same as R1-R5)

    f16* whi = (f16*)(ws + W_WHI);
    f16* wlo = (f16*)(ws + W_WLO);

    k0w<<<2359296 / 256, 256, 0, stream>>>(conv_w, whi, wlo);
    k1_mfma<<<dim3(32, 4, 4), 256, 0, stream>>>(x, whi, wlo, conv_b, ws + W_H);
    k2_conv1<<<dim3(64, 4), 256, 0, stream>>>(ws + W_H, score_w, score_b, loc_w, loc_b, out);
    // zero hist1 + cnt + cuts/cums + hist2 + hist3 (aliases h -> zero AFTER K2)
    hipMemsetAsync(ws + W_HIST, 0, (size_t)(W_H3 + 16384 - W_HIST) * 4, stream);
    k3_prop<<<dim3(144, 4), 256, 0, stream>>>(out, ws + W_R4, ws + W_SK, (int*)(ws + W_HIST));
    // level 1: cut1 over score bits 20..31
    k4scan<<<1, 256, 0, stream>>>((const int*)(ws + W_HIST), (const int*)(ws + W_ZERO),
                                  (int*)(ws + W_CUT), (int*)(ws + W_NHI1));
    // level 2: score bits 8..19 within cut1 bin
    k4h<<<dim3(144, 4), 256, 0, stream>>>(ws + W_SK, (const int*)(ws + W_CUT),
                                          (const int*)(ws + W_CUT2), (int*)(ws + W_H2), 2);
    k4scan<<<1, 256, 0, stream>>>((const int*)(ws + W_H2), (const int*)(ws + W_NHI1),
                                  (int*)(ws + W_CUT2), (int*)(ws + W_NHI2));
    // level 3: index bits (ties) within cut1&cut2 bins -> bin size <= 16
    k4h<<<dim3(144, 4), 256, 0, stream>>>(ws + W_SK, (const int*)(ws + W_CUT),
                                          (const int*)(ws + W_CUT2), (int*)(ws + W_H3), 3);
    k4scan<<<1, 256, 0, stream>>>((const int*)(ws + W_H3), (const int*)(ws + W_NHI2),
                                  (int*)(ws + W_CUT3), (int*)(ws + W_NHI3));
    k4c_compact<<<dim3(144, 4), 256, 0, stream>>>(ws + W_SK, (const int*)(ws + W_CUT),
                                                  (const int*)(ws + W_CUT2),
                                                  (const int*)(ws + W_CUT3),
                                                  (int*)(ws + W_CNT),
                                                  (unsigned long long*)(ws + W_CKEY));
    k4d_sort<<<BATCH, 1024, 0, stream>>>((const int*)(ws + W_CNT),
                                         (const unsigned long long*)(ws + W_CKEY),
                                         ws + W_R4, ws + W_RS, (int*)(ws + W_VS));
    k5_mat<<<dim3(NW, BATCH), 256, 0, stream>>>(ws + W_RS, (unsigned long long*)(ws + W_MAT));
    k5_scan<<<BATCH, 64, 0, stream>>>((const unsigned long long*)(ws + W_MAT),
                                      ws + W_RS, (const int*)(ws + W_VS), out);
}